// Round 1
// baseline (757.617 us; speedup 1.0000x reference)
//
#include <hip/hip_runtime.h>
#include <hip/hip_bf16.h>
#include <math.h>

#define NQ   2500
#define CDIM 256
#define NKV  5000
#define NH   8
#define DH   32
#define SPLITS 4
#define KEYS_PER_SPLIT 1250
#define TILES_PER_SPLIT 20   // 19*64 + 34

// ---------------- build kv = [query ; warp_prev(prev_bev)] ----------------
__global__ __launch_bounds__(256) void k_build_kv(
    const float* __restrict__ query, const float* __restrict__ prev,
    const float* __restrict__ ego, float* __restrict__ kv)
{
  int row = blockIdx.x, c = threadIdx.x;
  if (row < NQ) { kv[(size_t)row*CDIM + c] = query[(size_t)row*CDIM + c]; return; }
  int n = row - NQ;
  float txm = ego[3], tym = ego[7];
  float yaw = atan2f(ego[4], ego[0]);
  float cs = cosf(yaw), sn = sinf(yaw);
  float dx = txm * (1.f/51.2f), dy = tym * (1.f/51.2f);
  int i = n / 50, j = n % 50;
  float gx = (2.f*j + 1.f)*(1.f/50.f) - 1.f;
  float gy = (2.f*i + 1.f)*(1.f/50.f) - 1.f;
  float px = cs*gx - sn*gy + dx;
  float py = sn*gx + cs*gy + dy;
  float xf = ((px + 1.f)*50.f - 1.f)*0.5f;
  float yf = ((py + 1.f)*50.f - 1.f)*0.5f;
  float x0f = floorf(xf), y0f = floorf(yf);
  int x0 = (int)x0f, y0 = (int)y0f;
  float wx = xf - x0f, wy = yf - y0f;
  float v00 = (x0  >=0 && x0  <50 && y0  >=0 && y0  <50) ? prev[((size_t)(y0*50+x0      ))*CDIM + c] : 0.f;
  float v10 = (x0+1>=0 && x0+1<50 && y0  >=0 && y0  <50) ? prev[((size_t)(y0*50+x0+1    ))*CDIM + c] : 0.f;
  float v01 = (x0  >=0 && x0  <50 && y0+1>=0 && y0+1<50) ? prev[((size_t)((y0+1)*50+x0  ))*CDIM + c] : 0.f;
  float v11 = (x0+1>=0 && x0+1<50 && y0+1>=0 && y0+1<50) ? prev[((size_t)((y0+1)*50+x0+1))*CDIM + c] : 0.f;
  float v = (v00*(1.f-wx) + v10*wx)*(1.f-wy) + (v01*(1.f-wx) + v11*wx)*wy;
  kv[(size_t)row*CDIM + c] = v;
}

// ---------------- img_feats (6,256,28,50) -> imgT (6,28,50,256) ----------------
__global__ __launch_bounds__(256) void k_transpose_img(
    const float* __restrict__ img, float* __restrict__ imgT)
{
  int b = blockIdx.x;          // n*28 + y
  int n = b / 28, y = b % 28;
  int c = threadIdx.x;
  for (int x = 0; x < 50; ++x)
    imgT[((size_t)((n*28 + y)*50 + x))*CDIM + c] =
      img[((size_t)(n*CDIM + c)*28 + y)*50 + x];
}

// ---------------- generic C = act(A @ W^T + bias [+ res]) ----------------
// A: M x K (row-major), W: N x K (row-major), C: M x N. 64x64 tile, BK=32.
__global__ __launch_bounds__(256) void k_gemm(
    const float* __restrict__ A, const float* __restrict__ W,
    const float* __restrict__ bias, const float* __restrict__ res,
    float* __restrict__ C, int M, int N, int K, int relu)
{
  __shared__ float As[32][64];
  __shared__ float Ws[32][64];
  const int tid = threadIdx.x;
  const int tx = tid & 15, ty = tid >> 4;
  const int m0 = blockIdx.y << 6, n0 = blockIdx.x << 6;
  const int r = tid >> 2, kq = tid & 3;
  float acc[4][4] = {};
  const float4 z4 = make_float4(0.f,0.f,0.f,0.f);
  for (int k0 = 0; k0 < K; k0 += 32) {
    float4 a0 = z4, a1 = z4, w0 = z4, w1 = z4;
    if (m0 + r < M) {
      const float* ap = A + (size_t)(m0+r)*K + k0;
      a0 = *(const float4*)(ap + kq*4);
      a1 = *(const float4*)(ap + kq*4 + 16);
    }
    if (n0 + r < N) {
      const float* wp = W + (size_t)(n0+r)*K + k0;
      w0 = *(const float4*)(wp + kq*4);
      w1 = *(const float4*)(wp + kq*4 + 16);
    }
    __syncthreads();
    const int kc = kq*4;
    As[kc+0][r]=a0.x; As[kc+1][r]=a0.y; As[kc+2][r]=a0.z; As[kc+3][r]=a0.w;
    As[kc+16][r]=a1.x; As[kc+17][r]=a1.y; As[kc+18][r]=a1.z; As[kc+19][r]=a1.w;
    Ws[kc+0][r]=w0.x; Ws[kc+1][r]=w0.y; Ws[kc+2][r]=w0.z; Ws[kc+3][r]=w0.w;
    Ws[kc+16][r]=w1.x; Ws[kc+17][r]=w1.y; Ws[kc+18][r]=w1.z; Ws[kc+19][r]=w1.w;
    __syncthreads();
    #pragma unroll
    for (int kk = 0; kk < 32; ++kk) {
      float4 av = *(const float4*)&As[kk][ty*4];
      float4 wv = *(const float4*)&Ws[kk][tx*4];
      float aa[4] = {av.x, av.y, av.z, av.w};
      float ww[4] = {wv.x, wv.y, wv.z, wv.w};
      #pragma unroll
      for (int i2 = 0; i2 < 4; ++i2)
        #pragma unroll
        for (int j2 = 0; j2 < 4; ++j2) acc[i2][j2] += aa[i2]*ww[j2];
    }
  }
  const float4 bv = *(const float4*)&bias[n0 + tx*4];
  const float bb[4] = {bv.x, bv.y, bv.z, bv.w};
  #pragma unroll
  for (int i2 = 0; i2 < 4; ++i2) {
    int m = m0 + ty*4 + i2;
    if (m >= M) continue;
    float o[4];
    #pragma unroll
    for (int j2 = 0; j2 < 4; ++j2) o[j2] = acc[i2][j2] + bb[j2];
    if (res) {
      float4 rv = *(const float4*)&res[(size_t)m*N + n0 + tx*4];
      o[0]+=rv.x; o[1]+=rv.y; o[2]+=rv.z; o[3]+=rv.w;
    }
    if (relu) {
      #pragma unroll
      for (int j2 = 0; j2 < 4; ++j2) o[j2] = fmaxf(o[j2], 0.f);
    }
    *(float4*)&C[(size_t)m*N + n0 + tx*4] = make_float4(o[0],o[1],o[2],o[3]);
  }
}

// ---------------- flash attention, key-split partials ----------------
// grid (40 qblocks, 8 heads, SPLITS). Per (q,h,split): m, l, unnormalized o.
__global__ __launch_bounds__(256) void k_flash(
    const float* __restrict__ Q, const float* __restrict__ K,
    const float* __restrict__ V, float* __restrict__ opart,
    float* __restrict__ mlp)
{
  __shared__ float Qd[32][64];   // [d][row]
  __shared__ float Kd[32][64];   // [d][key]
  __shared__ float Vk[64][36];   // [key][d] (+4 pad)
  __shared__ float Ps[64][68];   // [key][row] (+4 pad, keeps 16B align)
  __shared__ float mrow[64], lrow[64], srow[64];
  const int tid = threadIdx.x;
  const int qb = blockIdx.x, h = blockIdx.y, sp = blockIdx.z;
  const int q0 = qb*64;
  const int r = tid >> 2, kq = tid & 3;
  const int ty = tid >> 4, tx = tid & 15;
  const int tz = tid >> 3, td = tid & 7;
  const float4 z4 = make_float4(0.f,0.f,0.f,0.f);
  {
    float4 a0 = z4, a1 = z4;
    if (q0 + r < NQ) {
      const float* qp = Q + (size_t)(q0+r)*CDIM + h*DH;
      a0 = *(const float4*)(qp + kq*4);
      a1 = *(const float4*)(qp + kq*4 + 16);
    }
    const int kc = kq*4;
    Qd[kc+0][r]=a0.x; Qd[kc+1][r]=a0.y; Qd[kc+2][r]=a0.z; Qd[kc+3][r]=a0.w;
    Qd[kc+16][r]=a1.x; Qd[kc+17][r]=a1.y; Qd[kc+18][r]=a1.z; Qd[kc+19][r]=a1.w;
  }
  if (tid < 64) { mrow[tid] = -INFINITY; lrow[tid] = 0.f; }
  float o0[4] = {0,0,0,0}, o1[4] = {0,0,0,0};
  const float sc = 0.1767766952966369f;   // 1/sqrt(32)
  for (int t = 0; t < TILES_PER_SPLIT; ++t) {
    const int kb = sp*KEYS_PER_SPLIT + t*64;
    const int nk = min(64, sp*KEYS_PER_SPLIT + KEYS_PER_SPLIT - kb);
    __syncthreads();   // previous tile's PV done; safe to restage
    {
      float4 k0 = z4, k1 = z4, v0 = z4, v1 = z4;
      if (r < nk) {
        const float* kp = K + (size_t)(kb+r)*CDIM + h*DH;
        const float* vp = V + (size_t)(kb+r)*CDIM + h*DH;
        k0 = *(const float4*)(kp + kq*4); k1 = *(const float4*)(kp + kq*4 + 16);
        v0 = *(const float4*)(vp + kq*4); v1 = *(const float4*)(vp + kq*4 + 16);
      }
      const int kc = kq*4;
      Kd[kc+0][r]=k0.x; Kd[kc+1][r]=k0.y; Kd[kc+2][r]=k0.z; Kd[kc+3][r]=k0.w;
      Kd[kc+16][r]=k1.x; Kd[kc+17][r]=k1.y; Kd[kc+18][r]=k1.z; Kd[kc+19][r]=k1.w;
      *(float4*)&Vk[r][kc]    = v0;
      *(float4*)&Vk[r][kc+16] = v1;
    }
    __syncthreads();
    // ---- S = Q K^T / sqrt(d), 4x4 micro-tile ----
    float s[4][4] = {};
    #pragma unroll
    for (int d = 0; d < 32; ++d) {
      float4 qv = *(const float4*)&Qd[d][ty*4];
      float4 kvv = *(const float4*)&Kd[d][tx*4];
      float qa[4] = {qv.x,qv.y,qv.z,qv.w};
      float ka[4] = {kvv.x,kvv.y,kvv.z,kvv.w};
      #pragma unroll
      for (int i2=0;i2<4;++i2)
        #pragma unroll
        for (int j2=0;j2<4;++j2) s[i2][j2] += qa[i2]*ka[j2];
    }
    #pragma unroll
    for (int i2=0;i2<4;++i2)
      #pragma unroll
      for (int j2=0;j2<4;++j2)
        s[i2][j2] = (tx*4 + j2 < nk) ? s[i2][j2]*sc : -1e30f;
    // ---- online softmax per row (16 tx lanes per row) ----
    #pragma unroll
    for (int i2=0;i2<4;++i2) {
      const int rr = ty*4 + i2;
      float mx = fmaxf(fmaxf(s[i2][0],s[i2][1]), fmaxf(s[i2][2],s[i2][3]));
      mx = fmaxf(mx, __shfl_xor(mx,1));
      mx = fmaxf(mx, __shfl_xor(mx,2));
      mx = fmaxf(mx, __shfl_xor(mx,4));
      mx = fmaxf(mx, __shfl_xor(mx,8));
      float mo = mrow[rr];
      float mn = fmaxf(mo, mx);
      float scl = __expf(mo - mn);
      float sum = 0.f;
      #pragma unroll
      for (int j2=0;j2<4;++j2) {
        float p = __expf(s[i2][j2] - mn);
        Ps[tx*4+j2][rr] = p;
        sum += p;
      }
      sum += __shfl_xor(sum,1);
      sum += __shfl_xor(sum,2);
      sum += __shfl_xor(sum,4);
      sum += __shfl_xor(sum,8);
      if (tx == 0) { mrow[rr] = mn; lrow[rr] = lrow[rr]*scl + sum; srow[rr] = scl; }
    }
    __syncthreads();
    // ---- PV: rows 2tz,2tz+1 ; dims td*4..td*4+3 ----
    const float s0 = srow[tz*2], s1 = srow[tz*2+1];
    #pragma unroll
    for (int j2=0;j2<4;++j2) { o0[j2]*=s0; o1[j2]*=s1; }
    #pragma unroll 8
    for (int k2=0;k2<64;++k2) {
      float2 p2 = *(const float2*)&Ps[k2][tz*2];
      float4 v4 = *(const float4*)&Vk[k2][td*4];
      float va[4]={v4.x,v4.y,v4.z,v4.w};
      #pragma unroll
      for (int j2=0;j2<4;++j2){ o0[j2]+=p2.x*va[j2]; o1[j2]+=p2.y*va[j2]; }
    }
  }
  const size_t obase = (size_t)(sp*NH + h)*NQ;
  {
    int q = q0 + tz*2;
    if (q < NQ)
      *(float4*)&opart[(obase + q)*DH + td*4] = make_float4(o0[0],o0[1],o0[2],o0[3]);
    if (q+1 < NQ)
      *(float4*)&opart[(obase + q + 1)*DH + td*4] = make_float4(o1[0],o1[1],o1[2],o1[3]);
  }
  if (tid < 64 && q0 + tid < NQ) {
    mlp[(obase + q0 + tid)*2 + 0] = mrow[tid];
    mlp[(obase + q0 + tid)*2 + 1] = lrow[tid];
  }
}

// ---------------- combine split partials ----------------
__global__ __launch_bounds__(256) void k_combine(
    const float* __restrict__ opart, const float* __restrict__ mlp,
    float* __restrict__ attn)
{
  const int q = blockIdx.x, t = threadIdx.x;
  const int h = t >> 5, d = t & 31;
  float ms[SPLITS], ls[SPLITS];
  float mstar = -INFINITY;
  #pragma unroll
  for (int s = 0; s < SPLITS; ++s) {
    size_t b = (size_t)(s*NH + h)*NQ + q;
    ms[s] = mlp[b*2]; ls[s] = mlp[b*2+1];
    mstar = fmaxf(mstar, ms[s]);
  }
  float num = 0.f, den = 0.f;
  #pragma unroll
  for (int s = 0; s < SPLITS; ++s) {
    float e = __expf(ms[s] - mstar);
    size_t b = (size_t)(s*NH + h)*NQ + q;
    num += opart[b*DH + d]*e;
    den += ls[s]*e;
  }
  attn[(size_t)q*CDIM + t] = num/den;
}

// ---------------- row LayerNorm: out = [post_res +] LN(x)*g + b ----------------
__global__ __launch_bounds__(256) void k_ln(
    const float* __restrict__ x, const float* __restrict__ g,
    const float* __restrict__ b, const float* __restrict__ post_res,
    float* __restrict__ out)
{
  const int row = blockIdx.x, c = threadIdx.x;
  const size_t idx = (size_t)row*CDIM + c;
  const float v = x[idx];
  __shared__ float red[4];
  float s = v;
  #pragma unroll
  for (int m = 1; m < 64; m <<= 1) s += __shfl_xor(s, m);
  if ((c & 63) == 0) red[c >> 6] = s;
  __syncthreads();
  const float mean = (red[0]+red[1]+red[2]+red[3]) * (1.f/256.f);
  const float dv = v - mean;
  __syncthreads();
  float s2 = dv*dv;
  #pragma unroll
  for (int m = 1; m < 64; m <<= 1) s2 += __shfl_xor(s2, m);
  if ((c & 63) == 0) red[c >> 6] = s2;
  __syncthreads();
  const float var = (red[0]+red[1]+red[2]+red[3]) * (1.f/256.f);
  float o = dv * rsqrtf(var + 1e-5f) * g[c] + b[c];
  if (post_res) o += post_res[idx];
  out[idx] = o;
}

// ---------------- fused attn_w GEMV + softmax(24) + point sampling + agg ----------------
__global__ __launch_bounds__(256) void k_sample_agg(
    const float* __restrict__ q1, const float* __restrict__ imgT,
    const float* __restrict__ l2i, const float* __restrict__ awW,
    const float* __restrict__ awb, float* __restrict__ agg)
{
  const int q = blockIdx.x, tid = threadIdx.x;
  __shared__ float qrow[256];
  __shared__ float wl[24];
  __shared__ float fwx[24], fwy[24];
  __shared__ int iv[24], ix[24], iy[24];
  qrow[tid] = q1[(size_t)q*CDIM + tid];
  __syncthreads();
  if (tid < 192) {                       // 8 lanes per e, e = 0..23
    const int e = tid >> 3, s2 = tid & 7;
    float acc = 0.f;
    for (int c = s2; c < 256; c += 8) acc += qrow[c]*awW[e*256 + c];
    acc += __shfl_xor(acc,1);
    acc += __shfl_xor(acc,2);
    acc += __shfl_xor(acc,4);
    if (s2 == 0) wl[e] = acc + awb[e];
  }
  if (tid < 24) {                        // sampling coords per (cam n, level z)
    const int e = tid, n = e >> 2, z = e & 3;
    const int iyq = q / 50, jxq = q % 50;
    const float rx = (jxq + 0.5f)*(1.f/50.f);
    const float ry = (iyq + 0.5f)*(1.f/50.f);
    const float rz = (z + 0.5f)*0.25f;
    const float X = rx*102.4f - 51.2f;
    const float Y = ry*102.4f - 51.2f;
    const float Z = rz*8.f - 5.f;
    const float* L = l2i + n*16;
    const float cx = L[0]*X + L[1]*Y + L[2]*Z  + L[3];
    const float cy = L[4]*X + L[5]*Y + L[6]*Z  + L[7];
    const float cd = L[8]*X + L[9]*Y + L[10]*Z + L[11];
    const float dn = fmaxf(cd, 1e-5f);
    const float u = cx/dn, vv = cy/dn;
    const float gx = (u*(1.f/49.f) - 0.5f)*2.f;
    const float gy = (vv*(1.f/27.f) - 0.5f)*2.f;
    const int ok = (cd > 1e-5f) && (gx > -1.f) && (gx < 1.f) && (gy > -1.f) && (gy < 1.f);
    const float xf = ((gx + 1.f)*50.f - 1.f)*0.5f;
    const float yf = ((gy + 1.f)*28.f - 1.f)*0.5f;
    const float x0f = floorf(xf), y0f = floorf(yf);
    iv[e] = ok; ix[e] = (int)x0f; iy[e] = (int)y0f;
    fwx[e] = xf - x0f; fwy[e] = yf - y0f;
  }
  __syncthreads();
  float mx = -INFINITY;
  #pragma unroll
  for (int e = 0; e < 24; ++e) mx = fmaxf(mx, wl[e]);
  float se = 0.f;
  #pragma unroll
  for (int e = 0; e < 24; ++e) se += __expf(wl[e]-mx);
  const float inv = 1.f/se;
  const int c = tid;
  float acc = 0.f;
  #pragma unroll
  for (int e = 0; e < 24; ++e) {
    if (!iv[e]) continue;
    const float w = __expf(wl[e]-mx)*inv;
    const int n = e >> 2;
    const int x0 = ix[e], y0 = iy[e];
    const float wx = fwx[e], wy = fwy[e];
    const size_t base = (size_t)(n*28)*50;
    float v00 = (x0  >=0 && x0  <50 && y0  >=0 && y0  <28) ? imgT[((base + (size_t)y0*50     + x0  ))*CDIM + c] : 0.f;
    float v10 = (x0+1>=0 && x0+1<50 && y0  >=0 && y0  <28) ? imgT[((base + (size_t)y0*50     + x0+1))*CDIM + c] : 0.f;
    float v01 = (x0  >=0 && x0  <50 && y0+1>=0 && y0+1<28) ? imgT[((base + (size_t)(y0+1)*50 + x0  ))*CDIM + c] : 0.f;
    float v11 = (x0+1>=0 && x0+1<50 && y0+1>=0 && y0+1<28) ? imgT[((base + (size_t)(y0+1)*50 + x0+1))*CDIM + c] : 0.f;
    acc += w * ((v00*(1.f-wx) + v10*wx)*(1.f-wy) + (v01*(1.f-wx) + v11*wx)*wy);
  }
  agg[(size_t)q*CDIM + c] = acc;
}

// ---------------- launcher ----------------
extern "C" void kernel_launch(void* const* d_in, const int* in_sizes, int n_in,
                              void* d_out, int out_size, void* d_ws, size_t ws_size,
                              hipStream_t stream)
{
  const float* query = (const float*)d_in[0];
  const float* prev  = (const float*)d_in[1];
  const float* img   = (const float*)d_in[2];
  const float* ego   = (const float*)d_in[3];
  const float* l2i   = (const float*)d_in[4];
  const float* awW   = (const float*)d_in[5];
  const float* awb   = (const float*)d_in[6];
  const float* scaW  = (const float*)d_in[7];
  const float* scab  = (const float*)d_in[8];
  const float* inW   = (const float*)d_in[9];
  const float* inb   = (const float*)d_in[10];
  const float* moW   = (const float*)d_in[11];
  const float* mob   = (const float*)d_in[12];
  const float* n1g   = (const float*)d_in[13];
  const float* n1b   = (const float*)d_in[14];
  const float* fW1   = (const float*)d_in[15];
  const float* fb1   = (const float*)d_in[16];
  const float* fW2   = (const float*)d_in[17];
  const float* fb2   = (const float*)d_in[18];
  const float* n2g   = (const float*)d_in[19];
  const float* n2b   = (const float*)d_in[20];
  float* out = (float*)d_out;
  float* ws  = (float*)d_ws;

  // workspace layout (floats), aliased by liveness:
  float* kv    = ws + 0;         // [5000,256]  dead after QKV GEMMs
  float* attn  = ws + 0;         //   reuse: [2500,256]
  float* tmp1  = ws + 640000;    //   reuse: [2500,256]
  float* Qb    = ws + 1280000;   // [2500,256]  dead after flash
  float* q1    = Qb;             //   reuse
  float* Kb    = ws + 1920000;   // [5000,256]  dead after flash
  float* aggb  = ws + 1920000;   //   reuse: [2500,256]
  float* q2    = ws + 2560000;   //   reuse: [2500,256]
  float* Vb    = ws + 3200000;   // [5000,256]  dead after flash
  float* hbuf  = Vb;             //   reuse: [2500,512]
  float* opart = ws + 4480000;   // [4,8,2500,32]  dead after combine
  float* h2    = opart;          //   reuse: [2500,256]
  float* mlp   = ws + 7040000;   // [4,8,2500,2]
  float* imgT  = ws + 7200000;   // [6,28,50,256]
  // total: 9,350,400 floats = 37.4 MB

  k_build_kv<<<NKV, 256, 0, stream>>>(query, prev, ego, kv);
  k_transpose_img<<<6*28, 256, 0, stream>>>(img, imgT);
  k_gemm<<<dim3(4,40), 256, 0, stream>>>(kv, inW,           inb,     nullptr, Qb, NQ,  256, 256, 0);
  k_gemm<<<dim3(4,79), 256, 0, stream>>>(kv, inW + 65536,   inb+256, nullptr, Kb, NKV, 256, 256, 0);
  k_gemm<<<dim3(4,79), 256, 0, stream>>>(kv, inW + 131072,  inb+512, nullptr, Vb, NKV, 256, 256, 0);
  k_flash<<<dim3(40, NH, SPLITS), 256, 0, stream>>>(Qb, Kb, Vb, opart, mlp);
  k_combine<<<NQ, 256, 0, stream>>>(opart, mlp, attn);
  k_gemm<<<dim3(4,40), 256, 0, stream>>>(attn, moW, mob, query, tmp1, NQ, 256, 256, 0);
  k_ln<<<NQ, 256, 0, stream>>>(tmp1, n1g, n1b, nullptr, q1);
  k_sample_agg<<<NQ, 256, 0, stream>>>(q1, imgT, l2i, awW, awb, aggb);
  k_gemm<<<dim3(4,40), 256, 0, stream>>>(aggb, scaW, scab, q1, q2, NQ, 256, 256, 0);
  k_gemm<<<dim3(8,40), 256, 0, stream>>>(q2, fW1, fb1, nullptr, hbuf, NQ, 512, 256, 1);
  k_gemm<<<dim3(4,40), 256, 0, stream>>>(hbuf, fW2, fb2, nullptr, h2, NQ, 256, 512, 0);
  k_ln<<<NQ, 256, 0, stream>>>(h2, n2g, n2b, q2, out);
}

// Round 2
// 269.521 us; speedup vs baseline: 2.8110x; 2.8110x over previous
//
#include <hip/hip_runtime.h>
#include <hip/hip_bf16.h>
#include <math.h>

#define NQ   2500
#define CDIM 256
#define NKV  5000
#define NH   8
#define DH   32
#define SPLITS 4
#define KEYS_PER_SPLIT 1250
#define TILES_PER_SPLIT 20   // 19*64 + 34

typedef __attribute__((ext_vector_type(8))) short bf16x8;
typedef __attribute__((ext_vector_type(4))) short short4v;
typedef __attribute__((ext_vector_type(4))) float f32x4;

__device__ inline short f2bf(float f) {
  union { float f; unsigned u; } v; v.f = f;
  unsigned r = v.u + 0x7FFFu + ((v.u >> 16) & 1u);   // RNE
  return (short)(r >> 16);
}

// ---------------- build kv = [query ; warp_prev(prev_bev)] ----------------
__global__ __launch_bounds__(256) void k_build_kv(
    const float* __restrict__ query, const float* __restrict__ prev,
    const float* __restrict__ ego, float* __restrict__ kv)
{
  int row = blockIdx.x, c = threadIdx.x;
  if (row < NQ) { kv[(size_t)row*CDIM + c] = query[(size_t)row*CDIM + c]; return; }
  int n = row - NQ;
  float txm = ego[3], tym = ego[7];
  float yaw = atan2f(ego[4], ego[0]);
  float cs = cosf(yaw), sn = sinf(yaw);
  float dx = txm * (1.f/51.2f), dy = tym * (1.f/51.2f);
  int i = n / 50, j = n % 50;
  float gx = (2.f*j + 1.f)*(1.f/50.f) - 1.f;
  float gy = (2.f*i + 1.f)*(1.f/50.f) - 1.f;
  float px = cs*gx - sn*gy + dx;
  float py = sn*gx + cs*gy + dy;
  float xf = ((px + 1.f)*50.f - 1.f)*0.5f;
  float yf = ((py + 1.f)*50.f - 1.f)*0.5f;
  float x0f = floorf(xf), y0f = floorf(yf);
  int x0 = (int)x0f, y0 = (int)y0f;
  float wx = xf - x0f, wy = yf - y0f;
  float v00 = (x0  >=0 && x0  <50 && y0  >=0 && y0  <50) ? prev[((size_t)(y0*50+x0      ))*CDIM + c] : 0.f;
  float v10 = (x0+1>=0 && x0+1<50 && y0  >=0 && y0  <50) ? prev[((size_t)(y0*50+x0+1    ))*CDIM + c] : 0.f;
  float v01 = (x0  >=0 && x0  <50 && y0+1>=0 && y0+1<50) ? prev[((size_t)((y0+1)*50+x0  ))*CDIM + c] : 0.f;
  float v11 = (x0+1>=0 && x0+1<50 && y0+1>=0 && y0+1<50) ? prev[((size_t)((y0+1)*50+x0+1))*CDIM + c] : 0.f;
  float v = (v00*(1.f-wx) + v10*wx)*(1.f-wy) + (v01*(1.f-wx) + v11*wx)*wy;
  kv[(size_t)row*CDIM + c] = v;
}

// ---------------- img_feats (6,256,28,50) -> imgT (6,28,50,256) ----------------
__global__ __launch_bounds__(256) void k_transpose_img(
    const float* __restrict__ img, float* __restrict__ imgT)
{
  int b = blockIdx.x;          // n*28 + y
  int n = b / 28, y = b % 28;
  int c = threadIdx.x;
  for (int x = 0; x < 50; ++x)
    imgT[((size_t)((n*28 + y)*50 + x))*CDIM + c] =
      img[((size_t)(n*CDIM + c)*28 + y)*50 + x];
}

// ---------------- generic GEMM: A(MxK) @ W(NxK)^T + bias ----------------
// mode 0: C f32 row-major (+res, +relu)
// mode 1: Cb bf16 row-major, value scaled by `scale`
// mode 2: Cb bf16 transposed [N][M]
__global__ __launch_bounds__(256) void k_gemm(
    const float* __restrict__ A, const float* __restrict__ W,
    const float* __restrict__ bias, const float* __restrict__ res,
    float* __restrict__ C, short* __restrict__ Cb,
    int M, int N, int K, int relu, int mode, float scale)
{
  __shared__ float As[32][64];
  __shared__ float Ws[32][64];
  const int tid = threadIdx.x;
  const int tx = tid & 15, ty = tid >> 4;
  const int m0 = blockIdx.y << 6, n0 = blockIdx.x << 6;
  const int r = tid >> 2, kq = tid & 3;
  float acc[4][4] = {};
  const float4 z4 = make_float4(0.f,0.f,0.f,0.f);
  for (int k0 = 0; k0 < K; k0 += 32) {
    float4 a0 = z4, a1 = z4, w0 = z4, w1 = z4;
    if (m0 + r < M) {
      const float* ap = A + (size_t)(m0+r)*K + k0;
      a0 = *(const float4*)(ap + kq*4);
      a1 = *(const float4*)(ap + kq*4 + 16);
    }
    if (n0 + r < N) {
      const float* wp = W + (size_t)(n0+r)*K + k0;
      w0 = *(const float4*)(wp + kq*4);
      w1 = *(const float4*)(wp + kq*4 + 16);
    }
    __syncthreads();
    const int kc = kq*4;
    As[kc+0][r]=a0.x; As[kc+1][r]=a0.y; As[kc+2][r]=a0.z; As[kc+3][r]=a0.w;
    As[kc+16][r]=a1.x; As[kc+17][r]=a1.y; As[kc+18][r]=a1.z; As[kc+19][r]=a1.w;
    Ws[kc+0][r]=w0.x; Ws[kc+1][r]=w0.y; Ws[kc+2][r]=w0.z; Ws[kc+3][r]=w0.w;
    Ws[kc+16][r]=w1.x; Ws[kc+17][r]=w1.y; Ws[kc+18][r]=w1.z; Ws[kc+19][r]=w1.w;
    __syncthreads();
    #pragma unroll
    for (int kk = 0; kk < 32; ++kk) {
      float4 av = *(const float4*)&As[kk][ty*4];
      float4 wv = *(const float4*)&Ws[kk][tx*4];
      float aa[4] = {av.x, av.y, av.z, av.w};
      float ww[4] = {wv.x, wv.y, wv.z, wv.w};
      #pragma unroll
      for (int i2 = 0; i2 < 4; ++i2)
        #pragma unroll
        for (int j2 = 0; j2 < 4; ++j2) acc[i2][j2] += aa[i2]*ww[j2];
    }
  }
  const float4 bv = *(const float4*)&bias[n0 + tx*4];
  const float bb[4] = {bv.x, bv.y, bv.z, bv.w};
  #pragma unroll
  for (int i2 = 0; i2 < 4; ++i2) {
    int m = m0 + ty*4 + i2;
    if (m >= M) continue;
    float o[4];
    #pragma unroll
    for (int j2 = 0; j2 < 4; ++j2) o[j2] = acc[i2][j2] + bb[j2];
    if (mode == 0) {
      if (res) {
        float4 rv = *(const float4*)&res[(size_t)m*N + n0 + tx*4];
        o[0]+=rv.x; o[1]+=rv.y; o[2]+=rv.z; o[3]+=rv.w;
      }
      if (relu) {
        #pragma unroll
        for (int j2 = 0; j2 < 4; ++j2) o[j2] = fmaxf(o[j2], 0.f);
      }
      *(float4*)&C[(size_t)m*N + n0 + tx*4] = make_float4(o[0],o[1],o[2],o[3]);
    } else if (mode == 1) {
      short4v s4;
      #pragma unroll
      for (int j2 = 0; j2 < 4; ++j2) s4[j2] = f2bf(o[j2]*scale);
      *(short4v*)&Cb[(size_t)m*N + n0 + tx*4] = s4;
    } else {
      #pragma unroll
      for (int j2 = 0; j2 < 4; ++j2)
        Cb[(size_t)(n0 + tx*4 + j2)*M + m] = f2bf(o[j2]);
    }
  }
}

// ---------------- bf16 MFMA flash attention (swapped QK^T), key-split ----------------
// grid (ceil(NQ/64), NH, SPLITS), 256 threads = 4 independent waves (16 q each).
// No LDS, no barriers. Per (sp,h,q): unnormalized o + (m,l).
__global__ __launch_bounds__(256) void k_flash2(
    const short* __restrict__ Qbf, const short* __restrict__ Kbf,
    const short* __restrict__ VbfT, float* __restrict__ opart,
    float* __restrict__ mlp)
{
  const int tid = threadIdx.x;
  const int wid = tid >> 6, lane = tid & 63;
  const int g = lane >> 4, c = lane & 15;
  const int qb = blockIdx.x, h = blockIdx.y, sp = blockIdx.z;
  const int qq = qb*64 + wid*16 + c;
  const int qld = min(qq, NQ-1);
  const bf16x8 qf = *(const bf16x8*)(Qbf + (size_t)qld*CDIM + h*DH + g*8);
  f32x4 oacc0 = {0.f,0.f,0.f,0.f}, oacc1 = {0.f,0.f,0.f,0.f};
  float m = -INFINITY, l = 0.f;
  const int kbase = sp*KEYS_PER_SPLIT;
  const short* vrow0 = VbfT + (size_t)(h*DH + c)*NKV;       // d-sub 0 row
  const short* vrow1 = VbfT + (size_t)(h*DH + 16 + c)*NKV;  // d-sub 1 row
  for (int t = 0; t < TILES_PER_SPLIT; ++t) {
    const int kb = kbase + t*64;
    const int nk = kbase + KEYS_PER_SPLIT - kb;  // >=64 except last tile (34)
    const f32x4 z = {0.f,0.f,0.f,0.f};
    f32x4 s0, s1, s2, s3;
    {
      const size_t doff = (size_t)h*DH + g*8;
      const int k0 = min(kb      + c, NKV-1);
      const int k1 = min(kb + 16 + c, NKV-1);
      const int k2 = min(kb + 32 + c, NKV-1);
      const int k3 = min(kb + 48 + c, NKV-1);
      bf16x8 kf0 = *(const bf16x8*)(Kbf + (size_t)k0*CDIM + doff);
      bf16x8 kf1 = *(const bf16x8*)(Kbf + (size_t)k1*CDIM + doff);
      bf16x8 kf2 = *(const bf16x8*)(Kbf + (size_t)k2*CDIM + doff);
      bf16x8 kf3 = *(const bf16x8*)(Kbf + (size_t)k3*CDIM + doff);
      s0 = __builtin_amdgcn_mfma_f32_16x16x32_bf16(kf0, qf, z, 0,0,0);
      s1 = __builtin_amdgcn_mfma_f32_16x16x32_bf16(kf1, qf, z, 0,0,0);
      s2 = __builtin_amdgcn_mfma_f32_16x16x32_bf16(kf2, qf, z, 0,0,0);
      s3 = __builtin_amdgcn_mfma_f32_16x16x32_bf16(kf3, qf, z, 0,0,0);
    }
    // lane holds S^T[key_local][q]: key_local = s*16 + g*4 + r, q = col c (lane-local!)
    float sv[16];
    #pragma unroll
    for (int r2=0;r2<4;++r2) {
      sv[r2]    = (      g*4+r2 < nk) ? s0[r2] : -1e30f;
      sv[4+r2]  = (16 +  g*4+r2 < nk) ? s1[r2] : -1e30f;
      sv[8+r2]  = (32 +  g*4+r2 < nk) ? s2[r2] : -1e30f;
      sv[12+r2] = (48 +  g*4+r2 < nk) ? s3[r2] : -1e30f;
    }
    float mx = sv[0];
    #pragma unroll
    for (int i=1;i<16;++i) mx = fmaxf(mx, sv[i]);
    mx = fmaxf(mx, __shfl_xor(mx, 16));
    mx = fmaxf(mx, __shfl_xor(mx, 32));
    const float mn = fmaxf(m, mx);
    const float scl = __expf(m - mn);   // first tile: exp(-inf)=0
    m = mn;
    float p[16]; float ps = 0.f;
    #pragma unroll
    for (int i=0;i<16;++i) { p[i] = __expf(sv[i] - mn); ps += p[i]; }
    ps += __shfl_xor(ps, 16);
    ps += __shfl_xor(ps, 32);
    l = l*scl + ps;
    #pragma unroll
    for (int r2=0;r2<4;++r2){ oacc0[r2]*=scl; oacc1[r2]*=scl; }
    bf16x8 pB0, pB1;
    #pragma unroll
    for (int i=0;i<8;++i){ pB0[i]=f2bf(p[i]); pB1[i]=f2bf(p[8+i]); }
    // PV: O^T[d][q] += V^T · P^T ; V^T frags loaded to match P^T's C-row key semantics
    {
      const int a0 = min(kb      + g*4, NKV-4);
      const int a1 = min(kb + 16 + g*4, NKV-4);
      const int a2 = min(kb + 32 + g*4, NKV-4);
      const int a3 = min(kb + 48 + g*4, NKV-4);
      short4v v00lo = *(const short4v*)(vrow0 + a0), v00hi = *(const short4v*)(vrow0 + a1);
      short4v v01lo = *(const short4v*)(vrow0 + a2), v01hi = *(const short4v*)(vrow0 + a3);
      short4v v10lo = *(const short4v*)(vrow1 + a0), v10hi = *(const short4v*)(vrow1 + a1);
      short4v v11lo = *(const short4v*)(vrow1 + a2), v11hi = *(const short4v*)(vrow1 + a3);
      bf16x8 A00 = {v00lo[0],v00lo[1],v00lo[2],v00lo[3], v00hi[0],v00hi[1],v00hi[2],v00hi[3]};
      bf16x8 A01 = {v01lo[0],v01lo[1],v01lo[2],v01lo[3], v01hi[0],v01hi[1],v01hi[2],v01hi[3]};
      bf16x8 A10 = {v10lo[0],v10lo[1],v10lo[2],v10lo[3], v10hi[0],v10hi[1],v10hi[2],v10hi[3]};
      bf16x8 A11 = {v11lo[0],v11lo[1],v11lo[2],v11lo[3], v11hi[0],v11hi[1],v11hi[2],v11hi[3]};
      oacc0 = __builtin_amdgcn_mfma_f32_16x16x32_bf16(A00, pB0, oacc0, 0,0,0);
      oacc0 = __builtin_amdgcn_mfma_f32_16x16x32_bf16(A01, pB1, oacc0, 0,0,0);
      oacc1 = __builtin_amdgcn_mfma_f32_16x16x32_bf16(A10, pB0, oacc1, 0,0,0);
      oacc1 = __builtin_amdgcn_mfma_f32_16x16x32_bf16(A11, pB1, oacc1, 0,0,0);
    }
  }
  if (qq < NQ) {
    const size_t ob = (size_t)(sp*NH + h)*NQ + qq;
    #pragma unroll
    for (int r2=0;r2<4;++r2) {
      opart[ob*DH + g*4 + r2]      = oacc0[r2];
      opart[ob*DH + 16 + g*4 + r2] = oacc1[r2];
    }
    if (g == 0) { mlp[ob*2] = m; mlp[ob*2+1] = l; }
  }
}

// ---------------- combine split partials ----------------
__global__ __launch_bounds__(256) void k_combine(
    const float* __restrict__ opart, const float* __restrict__ mlp,
    float* __restrict__ attn)
{
  const int q = blockIdx.x, t = threadIdx.x;
  const int h = t >> 5, d = t & 31;
  float ms[SPLITS], ls[SPLITS];
  float mstar = -INFINITY;
  #pragma unroll
  for (int s = 0; s < SPLITS; ++s) {
    size_t b = (size_t)(s*NH + h)*NQ + q;
    ms[s] = mlp[b*2]; ls[s] = mlp[b*2+1];
    mstar = fmaxf(mstar, ms[s]);
  }
  float num = 0.f, den = 0.f;
  #pragma unroll
  for (int s = 0; s < SPLITS; ++s) {
    float e = __expf(ms[s] - mstar);
    size_t b = (size_t)(s*NH + h)*NQ + q;
    num += opart[b*DH + d]*e;
    den += ls[s]*e;
  }
  attn[(size_t)q*CDIM + t] = num/den;
}

// ---------------- row LayerNorm: out = [post_res +] LN(x)*g + b ----------------
__global__ __launch_bounds__(256) void k_ln(
    const float* __restrict__ x, const float* __restrict__ g,
    const float* __restrict__ b, const float* __restrict__ post_res,
    float* __restrict__ out)
{
  const int row = blockIdx.x, c = threadIdx.x;
  const size_t idx = (size_t)row*CDIM + c;
  const float v = x[idx];
  __shared__ float red[4];
  float s = v;
  #pragma unroll
  for (int m = 1; m < 64; m <<= 1) s += __shfl_xor(s, m);
  if ((c & 63) == 0) red[c >> 6] = s;
  __syncthreads();
  const float mean = (red[0]+red[1]+red[2]+red[3]) * (1.f/256.f);
  const float dv = v - mean;
  __syncthreads();
  float s2 = dv*dv;
  #pragma unroll
  for (int m = 1; m < 64; m <<= 1) s2 += __shfl_xor(s2, m);
  if ((c & 63) == 0) red[c >> 6] = s2;
  __syncthreads();
  const float var = (red[0]+red[1]+red[2]+red[3]) * (1.f/256.f);
  float o = dv * rsqrtf(var + 1e-5f) * g[c] + b[c];
  if (post_res) o += post_res[idx];
  out[idx] = o;
}

// ---------------- fused attn_w GEMV + softmax(24) + point sampling + agg ----------------
__global__ __launch_bounds__(256) void k_sample_agg(
    const float* __restrict__ q1, const float* __restrict__ imgT,
    const float* __restrict__ l2i, const float* __restrict__ awW,
    const float* __restrict__ awb, float* __restrict__ agg)
{
  const int q = blockIdx.x, tid = threadIdx.x;
  __shared__ float qrow[256];
  __shared__ float wl[24];
  __shared__ float fwx[24], fwy[24];
  __shared__ int iv[24], ix[24], iy[24];
  qrow[tid] = q1[(size_t)q*CDIM + tid];
  __syncthreads();
  if (tid < 192) {
    const int e = tid >> 3, s2 = tid & 7;
    float acc = 0.f;
    for (int c = s2; c < 256; c += 8) acc += qrow[c]*awW[e*256 + c];
    acc += __shfl_xor(acc,1);
    acc += __shfl_xor(acc,2);
    acc += __shfl_xor(acc,4);
    if (s2 == 0) wl[e] = acc + awb[e];
  }
  if (tid < 24) {
    const int e = tid, n = e >> 2, z = e & 3;
    const int iyq = q / 50, jxq = q % 50;
    const float rx = (jxq + 0.5f)*(1.f/50.f);
    const float ry = (iyq + 0.5f)*(1.f/50.f);
    const float rz = (z + 0.5f)*0.25f;
    const float X = rx*102.4f - 51.2f;
    const float Y = ry*102.4f - 51.2f;
    const float Z = rz*8.f - 5.f;
    const float* L = l2i + n*16;
    const float cx = L[0]*X + L[1]*Y + L[2]*Z  + L[3];
    const float cy = L[4]*X + L[5]*Y + L[6]*Z  + L[7];
    const float cd = L[8]*X + L[9]*Y + L[10]*Z + L[11];
    const float dn = fmaxf(cd, 1e-5f);
    const float u = cx/dn, vv = cy/dn;
    const float gx = (u*(1.f/49.f) - 0.5f)*2.f;
    const float gy = (vv*(1.f/27.f) - 0.5f)*2.f;
    const int ok = (cd > 1e-5f) && (gx > -1.f) && (gx < 1.f) && (gy > -1.f) && (gy < 1.f);
    const float xf = ((gx + 1.f)*50.f - 1.f)*0.5f;
    const float yf = ((gy + 1.f)*28.f - 1.f)*0.5f;
    const float x0f = floorf(xf), y0f = floorf(yf);
    iv[e] = ok; ix[e] = (int)x0f; iy[e] = (int)y0f;
    fwx[e] = xf - x0f; fwy[e] = yf - y0f;
  }
  __syncthreads();
  float mx = -INFINITY;
  #pragma unroll
  for (int e = 0; e < 24; ++e) mx = fmaxf(mx, wl[e]);
  float se = 0.f;
  #pragma unroll
  for (int e = 0; e < 24; ++e) se += __expf(wl[e]-mx);
  const float inv = 1.f/se;
  const int c = tid;
  float acc = 0.f;
  #pragma unroll
  for (int e = 0; e < 24; ++e) {
    if (!iv[e]) continue;
    const float w = __expf(wl[e]-mx)*inv;
    const int n = e >> 2;
    const int x0 = ix[e], y0 = iy[e];
    const float wx = fwx[e], wy = fwy[e];
    const size_t base = (size_t)(n*28)*50;
    float v00 = (x0  >=0 && x0  <50 && y0  >=0 && y0  <28) ? imgT[((base + (size_t)y0*50     + x0  ))*CDIM + c] : 0.f;
    float v10 = (x0+1>=0 && x0+1<50 && y0  >=0 && y0  <28) ? imgT[((base + (size_t)y0*50     + x0+1))*CDIM + c] : 0.f;
    float v01 = (x0  >=0 && x0  <50 && y0+1>=0 && y0+1<28) ? imgT[((base + (size_t)(y0+1)*50 + x0  ))*CDIM + c] : 0.f;
    float v11 = (x0+1>=0 && x0+1<50 && y0+1>=0 && y0+1<28) ? imgT[((base + (size_t)(y0+1)*50 + x0+1))*CDIM + c] : 0.f;
    acc += w * ((v00*(1.f-wx) + v10*wx)*(1.f-wy) + (v01*(1.f-wx) + v11*wx)*wy);
  }
  agg[(size_t)q*CDIM + c] = acc;
}

// ---------------- launcher ----------------
extern "C" void kernel_launch(void* const* d_in, const int* in_sizes, int n_in,
                              void* d_out, int out_size, void* d_ws, size_t ws_size,
                              hipStream_t stream)
{
  const float* query = (const float*)d_in[0];
  const float* prev  = (const float*)d_in[1];
  const float* img   = (const float*)d_in[2];
  const float* ego   = (const float*)d_in[3];
  const float* l2i   = (const float*)d_in[4];
  const float* awW   = (const float*)d_in[5];
  const float* awb   = (const float*)d_in[6];
  const float* scaW  = (const float*)d_in[7];
  const float* scab  = (const float*)d_in[8];
  const float* inW   = (const float*)d_in[9];
  const float* inb   = (const float*)d_in[10];
  const float* moW   = (const float*)d_in[11];
  const float* mob   = (const float*)d_in[12];
  const float* n1g   = (const float*)d_in[13];
  const float* n1b   = (const float*)d_in[14];
  const float* fW1   = (const float*)d_in[15];
  const float* fb1   = (const float*)d_in[16];
  const float* fW2   = (const float*)d_in[17];
  const float* fb2   = (const float*)d_in[18];
  const float* n2g   = (const float*)d_in[19];
  const float* n2b   = (const float*)d_in[20];
  float* out = (float*)d_out;
  float* ws  = (float*)d_ws;

  // workspace layout (float offsets), aliased by liveness; total 7,750,400 f = 31.0 MB
  float* kv    = ws + 0;          // [5000,256] f32; dead after QKV GEMMs
  float* attn  = ws + 0;          //   reuse: [2500,256]
  float* tmp1  = ws + 640000;     //   reuse: [2500,256]
  short* Qbf   = (short*)(ws + 1280000);  // [2500,256] bf16 (pre-scaled 1/sqrt(32))
  short* Kbf   = (short*)(ws + 1600000);  // [5000,256] bf16
  short* VbfT  = (short*)(ws + 2240000);  // [256,5000] bf16 (per-head V^T)
  float* hbuf  = ws + 1600000;    //   reuse after flash: [2500,512]
  float* opart = ws + 2880000;    // [4,8,2500,32] f32; dead after combine
  float* q1    = ws + 2880000;    //   reuse: [2500,256]
  float* aggb  = ws + 3520000;    //   reuse: [2500,256]
  float* q2    = ws + 4160000;    //   reuse: [2500,256]
  float* h2    = ws + 4800000;    //   reuse: [2500,256]
  float* mlp   = ws + 5440000;    // [4,8,2500,2]
  float* imgT  = ws + 5600000;    // [6,28,50,256]

  k_build_kv<<<NKV, 256, 0, stream>>>(query, prev, ego, kv);
  k_transpose_img<<<6*28, 256, 0, stream>>>(img, imgT);
  // QKV projections -> bf16 (Q pre-scaled by 1/sqrt(32); V stored transposed)
  k_gemm<<<dim3(4,40), 256, 0, stream>>>(kv, inW,          inb,     nullptr, nullptr, Qbf,  NQ,  256, 256, 0, 1, 0.1767766952966369f);
  k_gemm<<<dim3(4,79), 256, 0, stream>>>(kv, inW + 65536,  inb+256, nullptr, nullptr, Kbf,  NKV, 256, 256, 0, 1, 1.0f);
  k_gemm<<<dim3(4,79), 256, 0, stream>>>(kv, inW + 131072, inb+512, nullptr, nullptr, VbfT, NKV, 256, 256, 0, 2, 1.0f);
  k_flash2<<<dim3(40, NH, SPLITS), 256, 0, stream>>>(Qbf, Kbf, VbfT, opart, mlp);
  k_combine<<<NQ, 256, 0, stream>>>(opart, mlp, attn);
  k_gemm<<<dim3(4,40), 256, 0, stream>>>(attn, moW, mob, query, tmp1, nullptr, NQ, 256, 256, 0, 0, 1.0f);
  k_ln<<<NQ, 256, 0, stream>>>(tmp1, n1g, n1b, nullptr, q1);
  k_sample_agg<<<NQ, 256, 0, stream>>>(q1, imgT, l2i, awW, awb, aggb);
  k_gemm<<<dim3(4,40), 256, 0, stream>>>(aggb, scaW, scab, q1, q2, nullptr, NQ, 256, 256, 0, 0, 1.0f);
  k_gemm<<<dim3(8,40), 256, 0, stream>>>(q2, fW1, fb1, nullptr, hbuf, nullptr, NQ, 512, 256, 1, 0, 1.0f);
  k_gemm<<<dim3(4,40), 256, 0, stream>>>(hbuf, fW2, fb2, nullptr, h2, nullptr, NQ, 256, 512, 0, 0, 1.0f);
  k_ln<<<NQ, 256, 0, stream>>>(h2, n2g, n2b, q2, out);
}

// Round 3
// 188.476 us; speedup vs baseline: 4.0197x; 1.4300x over previous
//
#include <hip/hip_runtime.h>
#include <hip/hip_bf16.h>
#include <math.h>

#define NQ   2500
#define CDIM 256
#define NKV  5000
#define NH   8
#define DH   32
#define SPLITS 8
#define KPS   625          // keys per split
#define FULLT 9            // 9 full 64-key tiles
#define TAILNK 49          // 625 - 9*64

typedef __attribute__((ext_vector_type(8))) short bf16x8;
typedef __attribute__((ext_vector_type(4))) short short4v;
typedef __attribute__((ext_vector_type(4))) float f32x4;

#define MFMA __builtin_amdgcn_mfma_f32_16x16x32_bf16

__device__ __forceinline__ short f2bf(float f) {          // RNE
  union { float f; unsigned u; } v; v.f = f;
  unsigned r = v.u + 0x7FFFu + ((v.u >> 16) & 1u);
  return (short)(r >> 16);
}
__device__ __forceinline__ float bf2f(unsigned short s) {
  union { unsigned u; float f; } x; x.u = ((unsigned)s) << 16; return x.f;
}
__device__ __forceinline__ unsigned pk_trunc(float a, float b) { // [lo=a, hi=b], truncation
  union { float f; unsigned u; } x, y; x.f = a; y.f = b;
  return (y.u & 0xFFFF0000u) | (x.u >> 16);
}
__device__ __forceinline__ unsigned cvt_pk_bf16(float a, float b) { // RNE packed (order-safe use only)
  unsigned r;
  asm("v_cvt_pk_bf16_f32 %0, %1, %2" : "=v"(r) : "v"(a), "v"(b));
  return r;
}
__device__ __forceinline__ float exp2_fast(float x) {
  float r; asm("v_exp_f32 %0, %1" : "=v"(r) : "v"(x)); return r;
}
__device__ __forceinline__ bf16x8 cat4(short4v a, short4v b) {
  bf16x8 r;
  r[0]=a[0]; r[1]=a[1]; r[2]=a[2]; r[3]=a[3];
  r[4]=b[0]; r[5]=b[1]; r[6]=b[2]; r[7]=b[3];
  return r;
}

// ---------------- build kv = [query ; warp_prev(prev_bev)] ----------------
__global__ __launch_bounds__(256) void k_build_kv(
    const float* __restrict__ query, const float* __restrict__ prev,
    const float* __restrict__ ego, float* __restrict__ kv)
{
  int row = blockIdx.x, c = threadIdx.x;
  if (row < NQ) { kv[(size_t)row*CDIM + c] = query[(size_t)row*CDIM + c]; return; }
  int n = row - NQ;
  float txm = ego[3], tym = ego[7];
  float yaw = atan2f(ego[4], ego[0]);
  float cs = cosf(yaw), sn = sinf(yaw);
  float dx = txm * (1.f/51.2f), dy = tym * (1.f/51.2f);
  int i = n / 50, j = n % 50;
  float gx = (2.f*j + 1.f)*(1.f/50.f) - 1.f;
  float gy = (2.f*i + 1.f)*(1.f/50.f) - 1.f;
  float px = cs*gx - sn*gy + dx;
  float py = sn*gx + cs*gy + dy;
  float xf = ((px + 1.f)*50.f - 1.f)*0.5f;
  float yf = ((py + 1.f)*50.f - 1.f)*0.5f;
  float x0f = floorf(xf), y0f = floorf(yf);
  int x0 = (int)x0f, y0 = (int)y0f;
  float wx = xf - x0f, wy = yf - y0f;
  float v00 = (x0  >=0 && x0  <50 && y0  >=0 && y0  <50) ? prev[((size_t)(y0*50+x0      ))*CDIM + c] : 0.f;
  float v10 = (x0+1>=0 && x0+1<50 && y0  >=0 && y0  <50) ? prev[((size_t)(y0*50+x0+1    ))*CDIM + c] : 0.f;
  float v01 = (x0  >=0 && x0  <50 && y0+1>=0 && y0+1<50) ? prev[((size_t)((y0+1)*50+x0  ))*CDIM + c] : 0.f;
  float v11 = (x0+1>=0 && x0+1<50 && y0+1>=0 && y0+1<50) ? prev[((size_t)((y0+1)*50+x0+1))*CDIM + c] : 0.f;
  float v = (v00*(1.f-wx) + v10*wx)*(1.f-wy) + (v01*(1.f-wx) + v11*wx)*wy;
  kv[(size_t)row*CDIM + c] = v;
}

// ---------------- img_feats (6,256,28,50) -> imgT (6,28,50,256) bf16 ----------------
__global__ __launch_bounds__(256) void k_transpose_img(
    const float* __restrict__ img, unsigned short* __restrict__ imgT)
{
  int b = blockIdx.x;          // n*28 + y
  int n = b / 28, y = b % 28;
  int c = threadIdx.x;
  for (int x = 0; x < 50; ++x)
    imgT[((size_t)((n*28 + y)*50 + x))*CDIM + c] =
      (unsigned short)f2bf(img[((size_t)(n*CDIM + c)*28 + y)*50 + x]);
}

// ---------------- MFMA GEMM: C = act(A(MxK) @ W(NxK)^T + bias [+res]) ----------------
// mode 0: C f32 row-major (+res, +relu). mode 1: Cb bf16 row-major ×scale. mode 2: Cb bf16 [N][M].
// BM=BN=64, BK=32, 4 waves. LDS layout [kg][row][8] -> conflict-free b128 frag reads.
__global__ __launch_bounds__(256) void k_gemm(
    const float* __restrict__ A, const float* __restrict__ W,
    const float* __restrict__ bias, const float* __restrict__ res,
    float* __restrict__ C, short* __restrict__ Cb,
    int M, int N, int K, int relu, int mode, float scale)
{
  __shared__ short Abf[4][64][8];
  __shared__ short Wbf[4][64][8];
  const int tid = threadIdx.x;
  const int lane = tid & 63, wid = tid >> 6;
  const int wm = wid >> 1, wn = wid & 1;
  const int g = lane >> 4, c = lane & 15;
  const int m0 = blockIdx.y << 6, n0 = blockIdx.x << 6;
  const int srow = tid >> 2, skg = tid & 3;
  f32x4 a00 = {0.f,0.f,0.f,0.f}, a01 = a00, a10 = a00, a11 = a00;
  const float4 z4 = make_float4(0.f,0.f,0.f,0.f);
  for (int k0 = 0; k0 < K; k0 += 32) {
    float4 fa0 = z4, fa1 = z4, fw0, fw1;
    if (m0 + srow < M) {
      const float* ap = A + (size_t)(m0+srow)*K + k0 + skg*8;
      fa0 = *(const float4*)ap; fa1 = *(const float4*)(ap+4);
    }
    {
      const float* wp = W + (size_t)(n0+srow)*K + k0 + skg*8;
      fw0 = *(const float4*)wp; fw1 = *(const float4*)(wp+4);
    }
    __syncthreads();   // prev iteration's frag reads done
    union { unsigned u[4]; bf16x8 v; } pa, pw;
    pa.u[0] = cvt_pk_bf16(fa0.x, fa0.y); pa.u[1] = cvt_pk_bf16(fa0.z, fa0.w);
    pa.u[2] = cvt_pk_bf16(fa1.x, fa1.y); pa.u[3] = cvt_pk_bf16(fa1.z, fa1.w);
    pw.u[0] = cvt_pk_bf16(fw0.x, fw0.y); pw.u[1] = cvt_pk_bf16(fw0.z, fw0.w);
    pw.u[2] = cvt_pk_bf16(fw1.x, fw1.y); pw.u[3] = cvt_pk_bf16(fw1.z, fw1.w);
    *(bf16x8*)&Abf[skg][srow][0] = pa.v;
    *(bf16x8*)&Wbf[skg][srow][0] = pw.v;
    __syncthreads();
    const bf16x8 fA0 = *(const bf16x8*)&Abf[g][wm*32      + c][0];
    const bf16x8 fA1 = *(const bf16x8*)&Abf[g][wm*32 + 16 + c][0];
    const bf16x8 fW0 = *(const bf16x8*)&Wbf[g][wn*32      + c][0];
    const bf16x8 fW1 = *(const bf16x8*)&Wbf[g][wn*32 + 16 + c][0];
    a00 = MFMA(fA0, fW0, a00, 0,0,0);
    a01 = MFMA(fA0, fW1, a01, 0,0,0);
    a10 = MFMA(fA1, fW0, a10, 0,0,0);
    a11 = MFMA(fA1, fW1, a11, 0,0,0);
  }
  // epilogue: lane holds C[m][n], m = m0+wm*32+mi*16+g*4+r, n = n0+wn*32+ni*16+c
  const float b0v = bias[n0 + wn*32 +      c];
  const float b1v = bias[n0 + wn*32 + 16 + c];
  #pragma unroll
  for (int mi = 0; mi < 2; ++mi) {
    #pragma unroll
    for (int r = 0; r < 4; ++r) {
      const int m = m0 + wm*32 + mi*16 + g*4 + r;
      if (m >= M) continue;
      float v0 = (mi ? a10[r] : a00[r]) + b0v;
      float v1 = (mi ? a11[r] : a01[r]) + b1v;
      const int n0c = n0 + wn*32 + c, n1c = n0c + 16;
      if (mode == 0) {
        if (res) { v0 += res[(size_t)m*N + n0c]; v1 += res[(size_t)m*N + n1c]; }
        if (relu) { v0 = fmaxf(v0, 0.f); v1 = fmaxf(v1, 0.f); }
        C[(size_t)m*N + n0c] = v0;
        C[(size_t)m*N + n1c] = v1;
      } else if (mode == 1) {
        Cb[(size_t)m*N + n0c] = f2bf(v0*scale);
        Cb[(size_t)m*N + n1c] = f2bf(v1*scale);
      } else {
        Cb[(size_t)n0c*M + m] = f2bf(v0);
        Cb[(size_t)n1c*M + m] = f2bf(v1);
      }
    }
  }
}

// ---------------- flash softmax+PV step for one 16-q fragment ----------------
__device__ __forceinline__ void softmax_pv(
    f32x4 s0, f32x4 s1, f32x4 s2, f32x4 s3, bool tail, int g,
    float& m, float& l, f32x4& oA, f32x4& oB,
    bf16x8 A0lo, bf16x8 A0hi, bf16x8 A1lo, bf16x8 A1hi)
{
  float sv[16];
  #pragma unroll
  for (int r=0;r<4;++r){ sv[r]=s0[r]; sv[4+r]=s1[r]; sv[8+r]=s2[r]; sv[12+r]=s3[r]; }
  if (tail) {
    #pragma unroll
    for (int i=0;i<16;++i) {
      const int kl = (i>>2)*16 + g*4 + (i&3);
      if (kl >= TAILNK) sv[i] = -1e30f;
    }
  }
  float mx = fmaxf(fmaxf(fmaxf(sv[0],sv[1]),fmaxf(sv[2],sv[3])),
                   fmaxf(fmaxf(sv[4],sv[5]),fmaxf(sv[6],sv[7])));
  mx = fmaxf(mx, fmaxf(fmaxf(fmaxf(sv[8],sv[9]),fmaxf(sv[10],sv[11])),
                       fmaxf(fmaxf(sv[12],sv[13]),fmaxf(sv[14],sv[15]))));
  mx = fmaxf(mx, __shfl_xor(mx, 16));
  mx = fmaxf(mx, __shfl_xor(mx, 32));
  const float mn = fmaxf(m, mx);
  const float scl = exp2_fast(m - mn);   // first tile: exp2(-inf)=0
  m = mn;
  float p[16]; float ps = 0.f;
  #pragma unroll
  for (int i=0;i<16;++i){ p[i] = exp2_fast(sv[i]-mn); ps += p[i]; }
  ps += __shfl_xor(ps, 16);
  ps += __shfl_xor(ps, 32);
  l = l*scl + ps;
  #pragma unroll
  for (int r=0;r<4;++r){ oA[r]*=scl; oB[r]*=scl; }
  union { unsigned u[4]; bf16x8 v; } b0, b1;
  #pragma unroll
  for (int i=0;i<4;++i) {
    b0.u[i] = pk_trunc(p[2*i],   p[2*i+1]);
    b1.u[i] = pk_trunc(p[8+2*i], p[8+2*i+1]);
  }
  oA = MFMA(A0lo, b0.v, oA, 0,0,0);
  oA = MFMA(A0hi, b1.v, oA, 0,0,0);
  oB = MFMA(A1lo, b0.v, oB, 0,0,0);
  oB = MFMA(A1hi, b1.v, oB, 0,0,0);
}

// ---------------- bf16 MFMA flash attention, 32 q/wave, exp2-domain ----------------
// grid (20, NH, SPLITS), 256 threads = 4 independent waves. No LDS/barriers.
__global__ __launch_bounds__(256) void k_flash2(
    const short* __restrict__ Qbf, const short* __restrict__ Kbf,
    const short* __restrict__ VbfT, short* __restrict__ opart,
    float* __restrict__ mlp)
{
  const int tid = threadIdx.x;
  const int wid = tid >> 6, lane = tid & 63;
  const int g = lane >> 4, c = lane & 15;
  const int h = blockIdx.y, sp = blockIdx.z;
  const int q0 = blockIdx.x*128 + wid*32;
  const int qa  = min(q0 +      c, NQ-1);
  const int qbq = min(q0 + 16 + c, NQ-1);
  const bf16x8 qf0 = *(const bf16x8*)(Qbf + (size_t)qa *CDIM + h*DH + g*8);
  const bf16x8 qf1 = *(const bf16x8*)(Qbf + (size_t)qbq*CDIM + h*DH + g*8);
  const int kbase = sp*KPS;
  const short* kbp = Kbf + (size_t)(kbase + c)*CDIM + h*DH + g*8;
  const short* vr0 = VbfT + (size_t)(h*DH +      c)*NKV + kbase;
  const short* vr1 = VbfT + (size_t)(h*DH + 16 + c)*NKV + kbase;
  const f32x4 z = {0.f,0.f,0.f,0.f};
  f32x4 o00 = z, o01 = z, o10 = z, o11 = z;
  float m0v = -INFINITY, l0 = 0.f, m1v = -INFINITY, l1 = 0.f;

  for (int t = 0; t < FULLT; ++t) {
    const int kt = t*64;
    const bf16x8 kf0 = *(const bf16x8*)(kbp + (size_t)(kt     )*CDIM);
    const bf16x8 kf1 = *(const bf16x8*)(kbp + (size_t)(kt + 16)*CDIM);
    const bf16x8 kf2 = *(const bf16x8*)(kbp + (size_t)(kt + 32)*CDIM);
    const bf16x8 kf3 = *(const bf16x8*)(kbp + (size_t)(kt + 48)*CDIM);
    const f32x4 s00 = MFMA(kf0, qf0, z, 0,0,0);
    const f32x4 s01 = MFMA(kf1, qf0, z, 0,0,0);
    const f32x4 s02 = MFMA(kf2, qf0, z, 0,0,0);
    const f32x4 s03 = MFMA(kf3, qf0, z, 0,0,0);
    const f32x4 s10 = MFMA(kf0, qf1, z, 0,0,0);
    const f32x4 s11 = MFMA(kf1, qf1, z, 0,0,0);
    const f32x4 s12 = MFMA(kf2, qf1, z, 0,0,0);
    const f32x4 s13 = MFMA(kf3, qf1, z, 0,0,0);
    const short4v x00 = *(const short4v*)(vr0 + kt      + g*4);
    const short4v x01 = *(const short4v*)(vr0 + kt + 16 + g*4);
    const short4v x02 = *(const short4v*)(vr0 + kt + 32 + g*4);
    const short4v x03 = *(const short4v*)(vr0 + kt + 48 + g*4);
    const short4v x10 = *(const short4v*)(vr1 + kt      + g*4);
    const short4v x11 = *(const short4v*)(vr1 + kt + 16 + g*4);
    const short4v x12 = *(const short4v*)(vr1 + kt + 32 + g*4);
    const short4v x13 = *(const short4v*)(vr1 + kt + 48 + g*4);
    const bf16x8 A0lo = cat4(x00, x01), A0hi = cat4(x02, x03);
    const bf16x8 A1lo = cat4(x10, x11), A1hi = cat4(x12, x13);
    softmax_pv(s00,s01,s02,s03, false, g, m0v, l0, o00, o01, A0lo, A0hi, A1lo, A1hi);
    softmax_pv(s10,s11,s12,s13, false, g, m1v, l1, o10, o11, A0lo, A0hi, A1lo, A1hi);
  }
  { // tail tile: 49 valid keys, clamped addresses, masked softmax
    const int kt = FULLT*64;   // 576
    const size_t doff = (size_t)h*DH + g*8;
    const int ka0 = min(kbase + kt +      c, NKV-1);
    const int ka1 = min(kbase + kt + 16 + c, NKV-1);
    const int ka2 = min(kbase + kt + 32 + c, NKV-1);
    const int ka3 = min(kbase + kt + 48 + c, NKV-1);
    const bf16x8 kf0 = *(const bf16x8*)(Kbf + (size_t)ka0*CDIM + doff);
    const bf16x8 kf1 = *(const bf16x8*)(Kbf + (size_t)ka1*CDIM + doff);
    const bf16x8 kf2 = *(const bf16x8*)(Kbf + (size_t)ka2*CDIM + doff);
    const bf16x8 kf3 = *(const bf16x8*)(Kbf + (size_t)ka3*CDIM + doff);
    const f32x4 s00 = MFMA(kf0, qf0, z, 0,0,0);
    const f32x4 s01 = MFMA(kf1, qf0, z, 0,0,0);
    const f32x4 s02 = MFMA(kf2, qf0, z, 0,0,0);
    const f32x4 s03 = MFMA(kf3, qf0, z, 0,0,0);
    const f32x4 s10 = MFMA(kf0, qf1, z, 0,0,0);
    const f32x4 s11 = MFMA(kf1, qf1, z, 0,0,0);
    const f32x4 s12 = MFMA(kf2, qf1, z, 0,0,0);
    const f32x4 s13 = MFMA(kf3, qf1, z, 0,0,0);
    const int o0 = min(kt      + g*4, KPS-4);
    const int o1 = min(kt + 16 + g*4, KPS-4);
    const int o2 = min(kt + 32 + g*4, KPS-4);
    const int o3 = min(kt + 48 + g*4, KPS-4);
    const short4v x00 = *(const short4v*)(vr0 + o0);
    const short4v x01 = *(const short4v*)(vr0 + o1);
    const short4v x02 = *(const short4v*)(vr0 + o2);
    const short4v x03 = *(const short4v*)(vr0 + o3);
    const short4v x10 = *(const short4v*)(vr1 + o0);
    const short4v x11 = *(const short4v*)(vr1 + o1);
    const short4v x12 = *(const short4v*)(vr1 + o2);
    const short4v x13 = *(const short4v*)(vr1 + o3);
    const bf16x8 A0lo = cat4(x00, x01), A0hi = cat4(x02, x03);
    const bf16x8 A1lo = cat4(x10, x11), A1hi = cat4(x12, x13);
    softmax_pv(s00,s01,s02,s03, true, g, m0v, l0, o00, o01, A0lo, A0hi, A1lo, A1hi);
    softmax_pv(s10,s11,s12,s13, true, g, m1v, l1, o10, o11, A0lo, A0hi, A1lo, A1hi);
  }
  const size_t ob0 = (size_t)(sp*NH + h)*NQ;
  const int qw0 = q0 + c;
  if (qw0 < NQ) {
    const size_t b = (ob0 + qw0)*DH;
    #pragma unroll
    for (int r=0;r<4;++r) {
      opart[b +      g*4 + r] = f2bf(o00[r]);
      opart[b + 16 + g*4 + r] = f2bf(o01[r]);
    }
    if (g == 0) { mlp[(ob0 + qw0)*2] = m0v; mlp[(ob0 + qw0)*2+1] = l0; }
  }
  const int qw1 = q0 + 16 + c;
  if (qw1 < NQ) {
    const size_t b = (ob0 + qw1)*DH;
    #pragma unroll
    for (int r=0;r<4;++r) {
      opart[b +      g*4 + r] = f2bf(o10[r]);
      opart[b + 16 + g*4 + r] = f2bf(o11[r]);
    }
    if (g == 0) { mlp[(ob0 + qw1)*2] = m1v; mlp[(ob0 + qw1)*2+1] = l1; }
  }
}

// ---------------- combine split partials (exp2 domain) ----------------
__global__ __launch_bounds__(256) void k_combine(
    const short* __restrict__ opart, const float* __restrict__ mlp,
    float* __restrict__ attn)
{
  const int q = blockIdx.x, t = threadIdx.x;
  const int h = t >> 5, d = t & 31;
  float ms[SPLITS], ls[SPLITS];
  float mstar = -INFINITY;
  #pragma unroll
  for (int s = 0; s < SPLITS; ++s) {
    size_t b = (size_t)(s*NH + h)*NQ + q;
    ms[s] = mlp[b*2]; ls[s] = mlp[b*2+1];
    mstar = fmaxf(mstar, ms[s]);
  }
  float num = 0.f, den = 0.f;
  #pragma unroll
  for (int s = 0; s < SPLITS; ++s) {
    float e = exp2_fast(ms[s] - mstar);
    size_t b = (size_t)(s*NH + h)*NQ + q;
    num += bf2f((unsigned short)opart[b*DH + d])*e;
    den += ls[s]*e;
  }
  attn[(size_t)q*CDIM + t] = num/den;
}

// ---------------- row LayerNorm: out = [post_res +] LN(x)*g + b ----------------
__global__ __launch_bounds__(256) void k_ln(
    const float* __restrict__ x, const float* __restrict__ g,
    const float* __restrict__ b, const float* __restrict__ post_res,
    float* __restrict__ out)
{
  const int row = blockIdx.x, c = threadIdx.x;
  const size_t idx = (size_t)row*CDIM + c;
  const float v = x[idx];
  __shared__ float red[4];
  float s = v;
  #pragma unroll
  for (int m = 1; m < 64; m <<= 1) s += __shfl_xor(s, m);
  if ((c & 63) == 0) red[c >> 6] = s;
  __syncthreads();
  const float mean = (red[0]+red[1]+red[2]+red[3]) * (1.f/256.f);
  const float dv = v - mean;
  __syncthreads();
  float s2 = dv*dv;
  #pragma unroll
  for (int m = 1; m < 64; m <<= 1) s2 += __shfl_xor(s2, m);
  if ((c & 63) == 0) red[c >> 6] = s2;
  __syncthreads();
  const float var = (red[0]+red[1]+red[2]+red[3]) * (1.f/256.f);
  float o = dv * rsqrtf(var + 1e-5f) * g[c] + b[c];
  if (post_res) o += post_res[idx];
  out[idx] = o;
}

// ---------------- fused attn_w GEMV + softmax(24) + point sampling + agg ----------------
__global__ __launch_bounds__(256) void k_sample_agg(
    const float* __restrict__ q1, const unsigned short* __restrict__ imgT,
    const float* __restrict__ l2i, const float* __restrict__ awW,
    const float* __restrict__ awb, float* __restrict__ agg)
{
  const int q = blockIdx.x, tid = threadIdx.x;
  __shared__ float qrow[256];
  __shared__ float wl[24];
  __shared__ float fwx[24], fwy[24];
  __shared__ int iv[24], ix[24], iy[24];
  qrow[tid] = q1[(size_t)q*CDIM + tid];
  __syncthreads();
  if (tid < 192) {
    const int e = tid >> 3, s2 = tid & 7;
    float acc = 0.f;
    for (int c = s2; c < 256; c += 8) acc += qrow[c]*awW[e*256 + c];
    acc += __shfl_xor(acc,1);
    acc += __shfl_xor(acc,2);
    acc += __shfl_xor(acc,4);
    if (s2 == 0) wl[e] = acc + awb[e];
  }
  if (tid < 24) {
    const int e = tid, n = e >> 2, z = e & 3;
    const int iyq = q / 50, jxq = q % 50;
    const float rx = (jxq + 0.5f)*(1.f/50.f);
    const float ry = (iyq + 0.5f)*(1.f/50.f);
    const float rz = (z + 0.5f)*0.25f;
    const float X = rx*102.4f - 51.2f;
    const float Y = ry*102.4f - 51.2f;
    const float Z = rz*8.f - 5.f;
    const float* L = l2i + n*16;
    const float cx = L[0]*X + L[1]*Y + L[2]*Z  + L[3];
    const float cy = L[4]*X + L[5]*Y + L[6]*Z  + L[7];
    const float cd = L[8]*X + L[9]*Y + L[10]*Z + L[11];
    const float dn = fmaxf(cd, 1e-5f);
    const float u = cx/dn, vv = cy/dn;
    const float gx = (u*(1.f/49.f) - 0.5f)*2.f;
    const float gy = (vv*(1.f/27.f) - 0.5f)*2.f;
    const int ok = (cd > 1e-5f) && (gx > -1.f) && (gx < 1.f) && (gy > -1.f) && (gy < 1.f);
    const float xf = ((gx + 1.f)*50.f - 1.f)*0.5f;
    const float yf = ((gy + 1.f)*28.f - 1.f)*0.5f;
    const float x0f = floorf(xf), y0f = floorf(yf);
    iv[e] = ok; ix[e] = (int)x0f; iy[e] = (int)y0f;
    fwx[e] = xf - x0f; fwy[e] = yf - y0f;
  }
  __syncthreads();
  float mx = -INFINITY;
  #pragma unroll
  for (int e = 0; e < 24; ++e) mx = fmaxf(mx, wl[e]);
  float se = 0.f;
  #pragma unroll
  for (int e = 0; e < 24; ++e) se += __expf(wl[e]-mx);
  const float inv = 1.f/se;
  const int c = tid;
  float acc = 0.f;
  #pragma unroll
  for (int e = 0; e < 24; ++e) {
    if (!iv[e]) continue;
    const float w = __expf(wl[e]-mx)*inv;
    const int n = e >> 2;
    const int x0 = ix[e], y0 = iy[e];
    const float wx = fwx[e], wy = fwy[e];
    const size_t base = (size_t)(n*28)*50;
    float v00 = (x0  >=0 && x0  <50 && y0  >=0 && y0  <28) ? bf2f(imgT[((base + (size_t)y0*50     + x0  ))*CDIM + c]) : 0.f;
    float v10 = (x0+1>=0 && x0+1<50 && y0  >=0 && y0  <28) ? bf2f(imgT[((base + (size_t)y0*50     + x0+1))*CDIM + c]) : 0.f;
    float v01 = (x0  >=0 && x0  <50 && y0+1>=0 && y0+1<28) ? bf2f(imgT[((base + (size_t)(y0+1)*50 + x0  ))*CDIM + c]) : 0.f;
    float v11 = (x0+1>=0 && x0+1<50 && y0+1>=0 && y0+1<28) ? bf2f(imgT[((base + (size_t)(y0+1)*50 + x0+1))*CDIM + c]) : 0.f;
    acc += w * ((v00*(1.f-wx) + v10*wx)*(1.f-wy) + (v01*(1.f-wx) + v11*wx)*wy);
  }
  agg[(size_t)q*CDIM + c] = acc;
}

// ---------------- launcher ----------------
extern "C" void kernel_launch(void* const* d_in, const int* in_sizes, int n_in,
                              void* d_out, int out_size, void* d_ws, size_t ws_size,
                              hipStream_t stream)
{
  const float* query = (const float*)d_in[0];
  const float* prev  = (const float*)d_in[1];
  const float* img   = (const float*)d_in[2];
  const float* ego   = (const float*)d_in[3];
  const float* l2i   = (const float*)d_in[4];
  const float* awW   = (const float*)d_in[5];
  const float* awb   = (const float*)d_in[6];
  const float* scaW  = (const float*)d_in[7];
  const float* scab  = (const float*)d_in[8];
  const float* inW   = (const float*)d_in[9];
  const float* inb   = (const float*)d_in[10];
  const float* moW   = (const float*)d_in[11];
  const float* mob   = (const float*)d_in[12];
  const float* n1g   = (const float*)d_in[13];
  const float* n1b   = (const float*)d_in[14];
  const float* fW1   = (const float*)d_in[15];
  const float* fb1   = (const float*)d_in[16];
  const float* fW2   = (const float*)d_in[17];
  const float* fb2   = (const float*)d_in[18];
  const float* n2g   = (const float*)d_in[19];
  const float* n2b   = (const float*)d_in[20];
  float* out = (float*)d_out;
  float* ws  = (float*)d_ws;

  // workspace layout (float offsets); total 8,115,200 floats = 32.5 MB
  float* kv    = ws;                        // [5000,256] f32; dead after QKV GEMMs
  float* attn  = ws;                        //   reuse: [2500,256]
  float* tmp1  = ws + 640000;               //   [2500,256]
  short* Qbf   = (short*)(ws + 1280000);    // [2500,256] bf16, pre-scaled (1/sqrt32)*log2e
  short* Kbf   = (short*)(ws + 1600000);    // [5000,256] bf16
  short* VbfT  = (short*)(ws + 2240000);    // [256,5000] bf16 (per-head V^T)
  short* opart = (short*)(ws + 2880000);    // [8,8,2500,32] bf16; dead after combine
  float* q1    = ws + 2880000;              //   reuse: [2500,256]
  float* aggb  = ws + 3520000;              //   reuse: [2500,256]
  float* q2    = ws + 4160000;              //   reuse: [2500,256]
  float* h2    = ws + 4800000;              //   reuse: [2500,256]
  float* hbuf  = ws + 5440000;              // [2500,512]
  float* mlp   = ws + 6720000;              // [8,8,2500,2] f32
  unsigned short* imgT = (unsigned short*)(ws + 7040000);  // [6,28,50,256] bf16

  const float qscale = 0.2550727452794943f;  // (1/sqrt(32)) * log2(e)

  k_build_kv<<<NKV, 256, 0, stream>>>(query, prev, ego, kv);
  k_transpose_img<<<6*28, 256, 0, stream>>>(img, imgT);
  k_gemm<<<dim3(4,40), 256, 0, stream>>>(kv, inW,          inb,     nullptr, nullptr, Qbf,  NQ,  256, 256, 0, 1, qscale);
  k_gemm<<<dim3(4,79), 256, 0, stream>>>(kv, inW + 65536,  inb+256, nullptr, nullptr, Kbf,  NKV, 256, 256, 0, 1, 1.0f);
  k_gemm<<<dim3(4,79), 256, 0, stream>>>(kv, inW + 131072, inb+512, nullptr, nullptr, VbfT, NKV, 256, 256, 0, 2, 1.0f);
  k_flash2<<<dim3(20, NH, SPLITS), 256, 0, stream>>>(Qbf, Kbf, VbfT, opart, mlp);
  k_combine<<<NQ, 256, 0, stream>>>(opart, mlp, attn);
  k_gemm<<<dim3(4,40), 256, 0, stream>>>(attn, moW, mob, query, tmp1, nullptr, NQ, 256, 256, 0, 0, 1.0f);
  k_ln<<<NQ, 256, 0, stream>>>(tmp1, n1g, n1b, nullptr, q1);
  k_sample_agg<<<NQ, 256, 0, stream>>>(q1, imgT, l2i, awW, awb, aggb);
  k_gemm<<<dim3(4,40), 256, 0, stream>>>(aggb, scaW, scab, q1, q2, nullptr, NQ, 256, 256, 0, 0, 1.0f);
  k_gemm<<<dim3(8,40), 256, 0, stream>>>(q2, fW1, fb1, nullptr, hbuf, nullptr, NQ, 512, 256, 1, 0, 1.0f);
  k_gemm<<<dim3(4,40), 256, 0, stream>>>(hbuf, fW2, fb2, nullptr, h2, nullptr, NQ, 256, 512, 0, 0, 1.0f);
  k_ln<<<NQ, 256, 0, stream>>>(h2, n2g, n2b, q2, out);
}

// Round 4
// 169.756 us; speedup vs baseline: 4.4630x; 1.1103x over previous
//
#include <hip/hip_runtime.h>
#include <hip/hip_bf16.h>
#include <math.h>

#define NQ   2500
#define CDIM 256
#define NKV  5000
#define NH   8
#define DH   32
#define SPLITS 8
#define KPS   625          // keys per split
#define FULLT 9            // 9 full 64-key tiles
#define TAILNK 49          // 625 - 9*64

typedef __attribute__((ext_vector_type(8))) short bf16x8;
typedef __attribute__((ext_vector_type(4))) short short4v;
typedef __attribute__((ext_vector_type(4))) float f32x4;

#define MFMA __builtin_amdgcn_mfma_f32_16x16x32_bf16

__device__ __forceinline__ short f2bf(float f) {          // RNE
  union { float f; unsigned u; } v; v.f = f;
  unsigned r = v.u + 0x7FFFu + ((v.u >> 16) & 1u);
  return (short)(r >> 16);
}
__device__ __forceinline__ float bf2f(unsigned short s) {
  union { unsigned u; float f; } x; x.u = ((unsigned)s) << 16; return x.f;
}
__device__ __forceinline__ unsigned pk_trunc(float a, float b) { // [lo=a, hi=b], truncation
  union { float f; unsigned u; } x, y; x.f = a; y.f = b;
  return (y.u & 0xFFFF0000u) | (x.u >> 16);
}
__device__ __forceinline__ unsigned cvt_pk_bf16(float a, float b) { // RNE packed (order-safe use only)
  unsigned r;
  asm("v_cvt_pk_bf16_f32 %0, %1, %2" : "=v"(r) : "v"(a), "v"(b));
  return r;
}
__device__ __forceinline__ float exp2_fast(float x) {
  float r; asm("v_exp_f32 %0, %1" : "=v"(r) : "v"(x)); return r;
}
__device__ __forceinline__ bf16x8 cat4(short4v a, short4v b) {
  bf16x8 r;
  r[0]=a[0]; r[1]=a[1]; r[2]=a[2]; r[3]=a[3];
  r[4]=b[0]; r[5]=b[1]; r[6]=b[2]; r[7]=b[3];
  return r;
}

// ---------------- build kv = [query ; warp_prev(prev_bev)] ----------------
__global__ __launch_bounds__(256) void k_build_kv(
    const float* __restrict__ query, const float* __restrict__ prev,
    const float* __restrict__ ego, float* __restrict__ kv)
{
  int row = blockIdx.x, c = threadIdx.x;
  if (row < NQ) { kv[(size_t)row*CDIM + c] = query[(size_t)row*CDIM + c]; return; }
  int n = row - NQ;
  float txm = ego[3], tym = ego[7];
  float yaw = atan2f(ego[4], ego[0]);
  float cs = cosf(yaw), sn = sinf(yaw);
  float dx = txm * (1.f/51.2f), dy = tym * (1.f/51.2f);
  int i = n / 50, j = n % 50;
  float gx = (2.f*j + 1.f)*(1.f/50.f) - 1.f;
  float gy = (2.f*i + 1.f)*(1.f/50.f) - 1.f;
  float px = cs*gx - sn*gy + dx;
  float py = sn*gx + cs*gy + dy;
  float xf = ((px + 1.f)*50.f - 1.f)*0.5f;
  float yf = ((py + 1.f)*50.f - 1.f)*0.5f;
  float x0f = floorf(xf), y0f = floorf(yf);
  int x0 = (int)x0f, y0 = (int)y0f;
  float wx = xf - x0f, wy = yf - y0f;
  float v00 = (x0  >=0 && x0  <50 && y0  >=0 && y0  <50) ? prev[((size_t)(y0*50+x0      ))*CDIM + c] : 0.f;
  float v10 = (x0+1>=0 && x0+1<50 && y0  >=0 && y0  <50) ? prev[((size_t)(y0*50+x0+1    ))*CDIM + c] : 0.f;
  float v01 = (x0  >=0 && x0  <50 && y0+1>=0 && y0+1<50) ? prev[((size_t)((y0+1)*50+x0  ))*CDIM + c] : 0.f;
  float v11 = (x0+1>=0 && x0+1<50 && y0+1>=0 && y0+1<50) ? prev[((size_t)((y0+1)*50+x0+1))*CDIM + c] : 0.f;
  float v = (v00*(1.f-wx) + v10*wx)*(1.f-wy) + (v01*(1.f-wx) + v11*wx)*wy;
  kv[(size_t)row*CDIM + c] = v;
}

// ---------------- img_feats (6,256,28,50) -> imgT (6,28,50,256) bf16 ----------------
__global__ __launch_bounds__(256) void k_transpose_img(
    const float* __restrict__ img, unsigned short* __restrict__ imgT)
{
  int b = blockIdx.x;          // n*28 + y
  int n = b / 28, y = b % 28;
  int c = threadIdx.x;
  for (int x = 0; x < 50; ++x)
    imgT[((size_t)((n*28 + y)*50 + x))*CDIM + c] =
      (unsigned short)f2bf(img[((size_t)(n*CDIM + c)*28 + y)*50 + x]);
}

// ---------------- MFMA GEMM: C = act(A(MxK) @ W(NxK)^T + bias [+res]) ----------------
// mode 0: C f32 row-major (+res, +relu). mode 1: Cb bf16 row-major ×scale. mode 2: Cb bf16 [N][M].
// BM=32, BN=64, BK=64, 4 waves (each 16x32). Padded LDS rows -> <=2-way staging conflicts.
__global__ __launch_bounds__(256) void k_gemm(
    const float* __restrict__ A, const float* __restrict__ W,
    const float* __restrict__ bias, const float* __restrict__ res,
    float* __restrict__ C, short* __restrict__ Cb,
    int M, int N, int K, int relu, int mode, float scale)
{
  __shared__ short Abf[8][33][8];   // [kgroup][row][8], row-padded
  __shared__ short Wbf[8][65][8];
  const int tid = threadIdx.x;
  const int lane = tid & 63, wid = tid >> 6;
  const int wm = wid >> 1, wn = wid & 1;
  const int g = lane >> 4, c = lane & 15;
  const int m0 = blockIdx.y << 5, n0 = blockIdx.x << 6;
  const int srow = tid >> 3, skq = tid & 7;
  f32x4 acc0 = {0.f,0.f,0.f,0.f}, acc1 = acc0;
  const float4 z4 = make_float4(0.f,0.f,0.f,0.f);
  for (int k0 = 0; k0 < K; k0 += 64) {
    float4 fa0 = z4, fa1 = z4;
    if (m0 + srow < M) {
      const float* ap = A + (size_t)(m0+srow)*K + k0 + skq*8;
      fa0 = *(const float4*)ap; fa1 = *(const float4*)(ap+4);
    }
    const float* wp0 = W + (size_t)(n0+srow)*K + k0 + skq*8;
    const float* wp1 = W + (size_t)(n0+32+srow)*K + k0 + skq*8;
    const float4 fw00 = *(const float4*)wp0, fw01 = *(const float4*)(wp0+4);
    const float4 fw10 = *(const float4*)wp1, fw11 = *(const float4*)(wp1+4);
    __syncthreads();   // prev iteration's frag reads done
    union { unsigned u[4]; bf16x8 v; } pa, pw0, pw1;
    pa.u[0]  = cvt_pk_bf16(fa0.x, fa0.y);  pa.u[1]  = cvt_pk_bf16(fa0.z, fa0.w);
    pa.u[2]  = cvt_pk_bf16(fa1.x, fa1.y);  pa.u[3]  = cvt_pk_bf16(fa1.z, fa1.w);
    pw0.u[0] = cvt_pk_bf16(fw00.x, fw00.y); pw0.u[1] = cvt_pk_bf16(fw00.z, fw00.w);
    pw0.u[2] = cvt_pk_bf16(fw01.x, fw01.y); pw0.u[3] = cvt_pk_bf16(fw01.z, fw01.w);
    pw1.u[0] = cvt_pk_bf16(fw10.x, fw10.y); pw1.u[1] = cvt_pk_bf16(fw10.z, fw10.w);
    pw1.u[2] = cvt_pk_bf16(fw11.x, fw11.y); pw1.u[3] = cvt_pk_bf16(fw11.z, fw11.w);
    *(bf16x8*)&Abf[skq][srow][0]      = pa.v;
    *(bf16x8*)&Wbf[skq][srow][0]      = pw0.v;
    *(bf16x8*)&Wbf[skq][32+srow][0]   = pw1.v;
    __syncthreads();
    #pragma unroll
    for (int s = 0; s < 2; ++s) {
      const bf16x8 fA  = *(const bf16x8*)&Abf[s*4+g][wm*16 + c][0];
      const bf16x8 fW0 = *(const bf16x8*)&Wbf[s*4+g][wn*32 + c][0];
      const bf16x8 fW1 = *(const bf16x8*)&Wbf[s*4+g][wn*32 + 16 + c][0];
      acc0 = MFMA(fA, fW0, acc0, 0,0,0);
      acc1 = MFMA(fA, fW1, acc1, 0,0,0);
    }
  }
  const int nc0 = n0 + wn*32 + c, nc1 = nc0 + 16;
  const float b0v = bias[nc0], b1v = bias[nc1];
  #pragma unroll
  for (int r = 0; r < 4; ++r) {
    const int m = m0 + wm*16 + g*4 + r;
    if (m >= M) continue;
    float v0 = acc0[r] + b0v;
    float v1 = acc1[r] + b1v;
    if (mode == 0) {
      if (res) { v0 += res[(size_t)m*N + nc0]; v1 += res[(size_t)m*N + nc1]; }
      if (relu) { v0 = fmaxf(v0, 0.f); v1 = fmaxf(v1, 0.f); }
      C[(size_t)m*N + nc0] = v0;
      C[(size_t)m*N + nc1] = v1;
    } else if (mode == 1) {
      Cb[(size_t)m*N + nc0] = f2bf(v0*scale);
      Cb[(size_t)m*N + nc1] = f2bf(v1*scale);
    } else {
      Cb[(size_t)nc0*M + m] = f2bf(v0);
      Cb[(size_t)nc1*M + m] = f2bf(v1);
    }
  }
}

// ---------------- flash softmax+PV step, T13 defer-max, lane-local l ----------------
__device__ __forceinline__ void softmax_pv(
    f32x4 s0, f32x4 s1, f32x4 s2, f32x4 s3, bool tail, int g,
    float& m, float& l, f32x4& oA, f32x4& oB,
    bf16x8 A0lo, bf16x8 A0hi, bf16x8 A1lo, bf16x8 A1hi)
{
  float sv[16];
  #pragma unroll
  for (int r=0;r<4;++r){ sv[r]=s0[r]; sv[4+r]=s1[r]; sv[8+r]=s2[r]; sv[12+r]=s3[r]; }
  if (tail) {
    #pragma unroll
    for (int i=0;i<16;++i) {
      const int kl = (i>>2)*16 + g*4 + (i&3);
      if (kl >= TAILNK) sv[i] = -1e30f;
    }
  }
  // lane-local max over this lane's 16 scores
  float mx = fmaxf(fmaxf(fmaxf(sv[0],sv[1]),fmaxf(sv[2],sv[3])),
                   fmaxf(fmaxf(sv[4],sv[5]),fmaxf(sv[6],sv[7])));
  mx = fmaxf(mx, fmaxf(fmaxf(fmaxf(sv[8],sv[9]),fmaxf(sv[10],sv[11])),
                       fmaxf(fmaxf(sv[12],sv[13]),fmaxf(sv[14],sv[15]))));
  // T13: only rescale when the running max actually needs to grow (wave-uniform)
  if (!__all(mx <= m + 8.f)) {
    float mm = fmaxf(mx, __shfl_xor(mx, 16));
    mm = fmaxf(mm, __shfl_xor(mm, 32));
    const float mn = fmaxf(m, mm);
    const float scl = exp2_fast(m - mn);   // first tile: exp2(-inf)=0
    m = mn;
    l *= scl;
    #pragma unroll
    for (int r=0;r<4;++r){ oA[r]*=scl; oB[r]*=scl; }
  }
  float p[16]; float ps = 0.f;
  #pragma unroll
  for (int i=0;i<16;++i){ p[i] = exp2_fast(sv[i]-m); ps += p[i]; }
  l += ps;                     // lane-local partial sum; combined across g at the end
  union { unsigned u[4]; bf16x8 v; } b0, b1;
  #pragma unroll
  for (int i=0;i<4;++i) {
    b0.u[i] = pk_trunc(p[2*i],   p[2*i+1]);
    b1.u[i] = pk_trunc(p[8+2*i], p[8+2*i+1]);
  }
  oA = MFMA(A0lo, b0.v, oA, 0,0,0);
  oA = MFMA(A0hi, b1.v, oA, 0,0,0);
  oB = MFMA(A1lo, b0.v, oB, 0,0,0);
  oB = MFMA(A1hi, b1.v, oB, 0,0,0);
}

// ---------------- bf16 MFMA flash attention, 32 q/wave, K-prefetch pipeline ----------------
// grid (20, NH, SPLITS), 256 threads = 4 independent waves. No LDS/barriers.
__global__ __launch_bounds__(256) void k_flash2(
    const short* __restrict__ Qbf, const short* __restrict__ Kbf,
    const short* __restrict__ VbfT, short* __restrict__ opart,
    float* __restrict__ mlp)
{
  const int tid = threadIdx.x;
  const int wid = tid >> 6, lane = tid & 63;
  const int g = lane >> 4, c = lane & 15;
  const int h = blockIdx.y, sp = blockIdx.z;
  const int q0 = blockIdx.x*128 + wid*32;
  const int qa  = min(q0 +      c, NQ-1);
  const int qbq = min(q0 + 16 + c, NQ-1);
  const bf16x8 qf0 = *(const bf16x8*)(Qbf + (size_t)qa *CDIM + h*DH + g*8);
  const bf16x8 qf1 = *(const bf16x8*)(Qbf + (size_t)qbq*CDIM + h*DH + g*8);
  const int kbase = sp*KPS;
  const short* kbp = Kbf + (size_t)(kbase + c)*CDIM + h*DH + g*8;
  const short* vr0 = VbfT + (size_t)(h*DH +      c)*NKV + kbase;
  const short* vr1 = VbfT + (size_t)(h*DH + 16 + c)*NKV + kbase;
  const f32x4 z = {0.f,0.f,0.f,0.f};
  f32x4 o00 = z, o01 = z, o10 = z, o11 = z;
  float m0v = -INFINITY, l0 = 0.f, m1v = -INFINITY, l1 = 0.f;

  // prologue: K tile 0
  bf16x8 kc0 = *(const bf16x8*)(kbp);
  bf16x8 kc1 = *(const bf16x8*)(kbp + (size_t)16*CDIM);
  bf16x8 kc2 = *(const bf16x8*)(kbp + (size_t)32*CDIM);
  bf16x8 kc3 = *(const bf16x8*)(kbp + (size_t)48*CDIM);

  #pragma unroll
  for (int t = 0; t < FULLT; ++t) {
    const int kt = t*64;
    const f32x4 s00 = MFMA(kc0, qf0, z, 0,0,0);
    const f32x4 s01 = MFMA(kc1, qf0, z, 0,0,0);
    const f32x4 s02 = MFMA(kc2, qf0, z, 0,0,0);
    const f32x4 s03 = MFMA(kc3, qf0, z, 0,0,0);
    const f32x4 s10 = MFMA(kc0, qf1, z, 0,0,0);
    const f32x4 s11 = MFMA(kc1, qf1, z, 0,0,0);
    const f32x4 s12 = MFMA(kc2, qf1, z, 0,0,0);
    const f32x4 s13 = MFMA(kc3, qf1, z, 0,0,0);
    if (t+1 < FULLT) {   // prefetch next K tile (in flight during softmax/PV)
      kc0 = *(const bf16x8*)(kbp + (size_t)(kt+64)*CDIM);
      kc1 = *(const bf16x8*)(kbp + (size_t)(kt+80)*CDIM);
      kc2 = *(const bf16x8*)(kbp + (size_t)(kt+96)*CDIM);
      kc3 = *(const bf16x8*)(kbp + (size_t)(kt+112)*CDIM);
    }
    const short4v x00 = *(const short4v*)(vr0 + kt      + g*4);
    const short4v x01 = *(const short4v*)(vr0 + kt + 16 + g*4);
    const short4v x02 = *(const short4v*)(vr0 + kt + 32 + g*4);
    const short4v x03 = *(const short4v*)(vr0 + kt + 48 + g*4);
    const short4v x10 = *(const short4v*)(vr1 + kt      + g*4);
    const short4v x11 = *(const short4v*)(vr1 + kt + 16 + g*4);
    const short4v x12 = *(const short4v*)(vr1 + kt + 32 + g*4);
    const short4v x13 = *(const short4v*)(vr1 + kt + 48 + g*4);
    const bf16x8 A0lo = cat4(x00, x01), A0hi = cat4(x02, x03);
    const bf16x8 A1lo = cat4(x10, x11), A1hi = cat4(x12, x13);
    softmax_pv(s00,s01,s02,s03, false, g, m0v, l0, o00, o01, A0lo, A0hi, A1lo, A1hi);
    softmax_pv(s10,s11,s12,s13, false, g, m1v, l1, o10, o11, A0lo, A0hi, A1lo, A1hi);
  }
  { // tail tile: 49 valid keys, clamped addresses, masked softmax
    const int kt = FULLT*64;   // 576
    const size_t doff = (size_t)h*DH + g*8;
    const int ka0 = min(kbase + kt +      c, NKV-1);
    const int ka1 = min(kbase + kt + 16 + c, NKV-1);
    const int ka2 = min(kbase + kt + 32 + c, NKV-1);
    const int ka3 = min(kbase + kt + 48 + c, NKV-1);
    const bf16x8 kf0 = *(const bf16x8*)(Kbf + (size_t)ka0*CDIM + doff);
    const bf16x8 kf1 = *(const bf16x8*)(Kbf + (size_t)ka1*CDIM + doff);
    const bf16x8 kf2 = *(const bf16x8*)(Kbf + (size_t)ka2*CDIM + doff);
    const bf16x8 kf3 = *(const bf16x8*)(Kbf + (size_t)ka3*CDIM + doff);
    const f32x4 s00 = MFMA(kf0, qf0, z, 0,0,0);
    const f32x4 s01 = MFMA(kf1, qf0, z, 0,0,0);
    const f32x4 s02 = MFMA(kf2, qf0, z, 0,0,0);
    const f32x4 s03 = MFMA(kf3, qf0, z, 0,0,0);
    const f32x4 s10 = MFMA(kf0, qf1, z, 0,0,0);
    const f32x4 s11 = MFMA(kf1, qf1, z, 0,0,0);
    const f32x4 s12 = MFMA(kf2, qf1, z, 0,0,0);
    const f32x4 s13 = MFMA(kf3, qf1, z, 0,0,0);
    const int o0 = min(kt      + g*4, KPS-4);
    const int o1 = min(kt + 16 + g*4, KPS-4);
    const int o2 = min(kt + 32 + g*4, KPS-4);
    const int o3 = min(kt + 48 + g*4, KPS-4);
    const short4v x00 = *(const short4v*)(vr0 + o0);
    const short4v x01 = *(const short4v*)(vr0 + o1);
    const short4v x02 = *(const short4v*)(vr0 + o2);
    const short4v x03 = *(const short4v*)(vr0 + o3);
    const short4v x10 = *(const short4v*)(vr1 + o0);
    const short4v x11 = *(const short4v*)(vr1 + o1);
    const short4v x12 = *(const short4v*)(vr1 + o2);
    const short4v x13 = *(const short4v*)(vr1 + o3);
    const bf16x8 A0lo = cat4(x00, x01), A0hi = cat4(x02, x03);
    const bf16x8 A1lo = cat4(x10, x11), A1hi = cat4(x12, x13);
    softmax_pv(s00,s01,s02,s03, true, g, m0v, l0, o00, o01, A0lo, A0hi, A1lo, A1hi);
    softmax_pv(s10,s11,s12,s13, true, g, m1v, l1, o10, o11, A0lo, A0hi, A1lo, A1hi);
  }
  // combine lane-local l across the 4 g-lanes of each q-column
  l0 += __shfl_xor(l0, 16); l0 += __shfl_xor(l0, 32);
  l1 += __shfl_xor(l1, 16); l1 += __shfl_xor(l1, 32);

  const size_t ob0 = (size_t)(sp*NH + h)*NQ;
  const int qw0 = q0 + c;
  if (qw0 < NQ) {
    const size_t b = (ob0 + qw0)*DH;
    #pragma unroll
    for (int r=0;r<4;++r) {
      opart[b +      g*4 + r] = f2bf(o00[r]);
      opart[b + 16 + g*4 + r] = f2bf(o01[r]);
    }
    if (g == 0) { mlp[(ob0 + qw0)*2] = m0v; mlp[(ob0 + qw0)*2+1] = l0; }
  }
  const int qw1 = q0 + 16 + c;
  if (qw1 < NQ) {
    const size_t b = (ob0 + qw1)*DH;
    #pragma unroll
    for (int r=0;r<4;++r) {
      opart[b +      g*4 + r] = f2bf(o10[r]);
      opart[b + 16 + g*4 + r] = f2bf(o11[r]);
    }
    if (g == 0) { mlp[(ob0 + qw1)*2] = m1v; mlp[(ob0 + qw1)*2+1] = l1; }
  }
}

// ---------------- combine split partials (exp2 domain) ----------------
__global__ __launch_bounds__(256) void k_combine(
    const short* __restrict__ opart, const float* __restrict__ mlp,
    float* __restrict__ attn)
{
  const int q = blockIdx.x, t = threadIdx.x;
  const int h = t >> 5, d = t & 31;
  float ms[SPLITS], ls[SPLITS];
  float mstar = -INFINITY;
  #pragma unroll
  for (int s = 0; s < SPLITS; ++s) {
    size_t b = (size_t)(s*NH + h)*NQ + q;
    ms[s] = mlp[b*2]; ls[s] = mlp[b*2+1];
    mstar = fmaxf(mstar, ms[s]);
  }
  float num = 0.f, den = 0.f;
  #pragma unroll
  for (int s = 0; s < SPLITS; ++s) {
    float e = exp2_fast(ms[s] - mstar);
    size_t b = (size_t)(s*NH + h)*NQ + q;
    num += bf2f((unsigned short)opart[b*DH + d])*e;
    den += ls[s]*e;
  }
  attn[(size_t)q*CDIM + t] = num/den;
}

// ---------------- row LayerNorm: out = [post_res +] LN(x)*g + b ----------------
__global__ __launch_bounds__(256) void k_ln(
    const float* __restrict__ x, const float* __restrict__ g,
    const float* __restrict__ b, const float* __restrict__ post_res,
    float* __restrict__ out)
{
  const int row = blockIdx.x, c = threadIdx.x;
  const size_t idx = (size_t)row*CDIM + c;
  const float v = x[idx];
  __shared__ float red[4];
  float s = v;
  #pragma unroll
  for (int m = 1; m < 64; m <<= 1) s += __shfl_xor(s, m);
  if ((c & 63) == 0) red[c >> 6] = s;
  __syncthreads();
  const float mean = (red[0]+red[1]+red[2]+red[3]) * (1.f/256.f);
  const float dv = v - mean;
  __syncthreads();
  float s2 = dv*dv;
  #pragma unroll
  for (int m = 1; m < 64; m <<= 1) s2 += __shfl_xor(s2, m);
  if ((c & 63) == 0) red[c >> 6] = s2;
  __syncthreads();
  const float var = (red[0]+red[1]+red[2]+red[3]) * (1.f/256.f);
  float o = dv * rsqrtf(var + 1e-5f) * g[c] + b[c];
  if (post_res) o += post_res[idx];
  out[idx] = o;
}

// ---------------- fused attn_w GEMV + softmax(24) + point sampling + agg ----------------
__global__ __launch_bounds__(256) void k_sample_agg(
    const float* __restrict__ q1, const unsigned short* __restrict__ imgT,
    const float* __restrict__ l2i, const float* __restrict__ awW,
    const float* __restrict__ awb, float* __restrict__ agg)
{
  const int q = blockIdx.x, tid = threadIdx.x;
  __shared__ float qrow[256];
  __shared__ float wl[24];
  __shared__ float fwx[24], fwy[24];
  __shared__ int iv[24], ix[24], iy[24];
  qrow[tid] = q1[(size_t)q*CDIM + tid];
  __syncthreads();
  if (tid < 192) {
    const int e = tid >> 3, s2 = tid & 7;
    float acc = 0.f;
    for (int c = s2; c < 256; c += 8) acc += qrow[c]*awW[e*256 + c];
    acc += __shfl_xor(acc,1);
    acc += __shfl_xor(acc,2);
    acc += __shfl_xor(acc,4);
    if (s2 == 0) wl[e] = acc + awb[e];
  }
  if (tid < 24) {
    const int e = tid, n = e >> 2, z = e & 3;
    const int iyq = q / 50, jxq = q % 50;
    const float rx = (jxq + 0.5f)*(1.f/50.f);
    const float ry = (iyq + 0.5f)*(1.f/50.f);
    const float rz = (z + 0.5f)*0.25f;
    const float X = rx*102.4f - 51.2f;
    const float Y = ry*102.4f - 51.2f;
    const float Z = rz*8.f - 5.f;
    const float* L = l2i + n*16;
    const float cx = L[0]*X + L[1]*Y + L[2]*Z  + L[3];
    const float cy = L[4]*X + L[5]*Y + L[6]*Z  + L[7];
    const float cd = L[8]*X + L[9]*Y + L[10]*Z + L[11];
    const float dn = fmaxf(cd, 1e-5f);
    const float u = cx/dn, vv = cy/dn;
    const float gx = (u*(1.f/49.f) - 0.5f)*2.f;
    const float gy = (vv*(1.f/27.f) - 0.5f)*2.f;
    const int ok = (cd > 1e-5f) && (gx > -1.f) && (gx < 1.f) && (gy > -1.f) && (gy < 1.f);
    const float xf = ((gx + 1.f)*50.f - 1.f)*0.5f;
    const float yf = ((gy + 1.f)*28.f - 1.f)*0.5f;
    const float x0f = floorf(xf), y0f = floorf(yf);
    iv[e] = ok; ix[e] = (int)x0f; iy[e] = (int)y0f;
    fwx[e] = xf - x0f; fwy[e] = yf - y0f;
  }
  __syncthreads();
  float mx = -INFINITY;
  #pragma unroll
  for (int e = 0; e < 24; ++e) mx = fmaxf(mx, wl[e]);
  float se = 0.f;
  #pragma unroll
  for (int e = 0; e < 24; ++e) se += __expf(wl[e]-mx);
  const float inv = 1.f/se;
  const int c = tid;
  float acc = 0.f;
  #pragma unroll
  for (int e = 0; e < 24; ++e) {
    if (!iv[e]) continue;
    const float w = __expf(wl[e]-mx)*inv;
    const int n = e >> 2;
    const int x0 = ix[e], y0 = iy[e];
    const float wx = fwx[e], wy = fwy[e];
    const size_t base = (size_t)(n*28)*50;
    float v00 = (x0  >=0 && x0  <50 && y0  >=0 && y0  <28) ? bf2f(imgT[((base + (size_t)y0*50     + x0  ))*CDIM + c]) : 0.f;
    float v10 = (x0+1>=0 && x0+1<50 && y0  >=0 && y0  <28) ? bf2f(imgT[((base + (size_t)y0*50     + x0+1))*CDIM + c]) : 0.f;
    float v01 = (x0  >=0 && x0  <50 && y0+1>=0 && y0+1<28) ? bf2f(imgT[((base + (size_t)(y0+1)*50 + x0  ))*CDIM + c]) : 0.f;
    float v11 = (x0+1>=0 && x0+1<50 && y0+1>=0 && y0+1<28) ? bf2f(imgT[((base + (size_t)(y0+1)*50 + x0+1))*CDIM + c]) : 0.f;
    acc += w * ((v00*(1.f-wx) + v10*wx)*(1.f-wy) + (v01*(1.f-wx) + v11*wx)*wy);
  }
  agg[(size_t)q*CDIM + c] = acc;
}

// ---------------- launcher ----------------
extern "C" void kernel_launch(void* const* d_in, const int* in_sizes, int n_in,
                              void* d_out, int out_size, void* d_ws, size_t ws_size,
                              hipStream_t stream)
{
  const float* query = (const float*)d_in[0];
  const float* prev  = (const float*)d_in[1];
  const float* img   = (const float*)d_in[2];
  const float* ego   = (const float*)d_in[3];
  const float* l2i   = (const float*)d_in[4];
  const float* awW   = (const float*)d_in[5];
  const float* awb   = (const float*)d_in[6];
  const float* scaW  = (const float*)d_in[7];
  const float* scab  = (const float*)d_in[8];
  const float* inW   = (const float*)d_in[9];
  const float* inb   = (const float*)d_in[10];
  const float* moW   = (const float*)d_in[11];
  const float* mob   = (const float*)d_in[12];
  const float* n1g   = (const float*)d_in[13];
  const float* n1b   = (const float*)d_in[14];
  const float* fW1   = (const float*)d_in[15];
  const float* fb1   = (const float*)d_in[16];
  const float* fW2   = (const float*)d_in[17];
  const float* fb2   = (const float*)d_in[18];
  const float* n2g   = (const float*)d_in[19];
  const float* n2b   = (const float*)d_in[20];
  float* out = (float*)d_out;
  float* ws  = (float*)d_ws;

  // workspace layout (float offsets); total 8,115,200 floats = 32.5 MB
  float* kv    = ws;                        // [5000,256] f32; dead after QKV GEMMs
  float* attn  = ws;                        //   reuse: [2500,256]
  float* tmp1  = ws + 640000;               //   [2500,256]
  short* Qbf   = (short*)(ws + 1280000);    // [2500,256] bf16, pre-scaled (1/sqrt32)*log2e
  short* Kbf   = (short*)(ws + 1600000);    // [5000,256] bf16
  short* VbfT  = (short*)(ws + 2240000);    // [256,5000] bf16 (per-head V^T)
  short* opart = (short*)(ws + 2880000);    // [8,8,2500,32] bf16; dead after combine
  float* q1    = ws + 2880000;              //   reuse: [2500,256]
  float* aggb  = ws + 3520000;              //   reuse: [2500,256]
  float* q2    = ws + 4160000;              //   reuse: [2500,256]
  float* h2    = ws + 4800000;              //   reuse: [2500,256]
  float* hbuf  = ws + 5440000;              // [2500,512]
  float* mlp   = ws + 6720000;              // [8,8,2500,2] f32
  unsigned short* imgT = (unsigned short*)(ws + 7040000);  // [6,28,50,256] bf16

  const float qscale = 0.2550727452794943f;  // (1/sqrt(32)) * log2(e)

  k_build_kv<<<NKV, 256, 0, stream>>>(query, prev, ego, kv);
  k_transpose_img<<<6*28, 256, 0, stream>>>(img, imgT);
  k_gemm<<<dim3(4,79),  256, 0, stream>>>(kv, inW,          inb,     nullptr, nullptr, Qbf,  NQ,  256, 256, 0, 1, qscale);
  k_gemm<<<dim3(4,157), 256, 0, stream>>>(kv, inW + 65536,  inb+256, nullptr, nullptr, Kbf,  NKV, 256, 256, 0, 1, 1.0f);
  k_gemm<<<dim3(4,157), 256, 0, stream>>>(kv, inW + 131072, inb+512, nullptr, nullptr, VbfT, NKV, 256, 256, 0, 2, 1.0f);
  k_flash2<<<dim3(20, NH, SPLITS), 256, 0, stream>>>(Qbf, Kbf, VbfT, opart, mlp);
  k_combine<<<NQ, 256, 0, stream>>>(opart, mlp, attn);
  k_gemm<<<dim3(4,79), 256, 0, stream>>>(attn, moW, mob, query, tmp1, nullptr, NQ, 256, 256, 0, 0, 1.0f);
  k_ln<<<NQ, 256, 0, stream>>>(tmp1, n1g, n1b, nullptr, q1);
  k_sample_agg<<<NQ, 256, 0, stream>>>(q1, imgT, l2i, awW, awb, aggb);
  k_gemm<<<dim3(4,79), 256, 0, stream>>>(aggb, scaW, scab, q1, q2, nullptr, NQ, 256, 256, 0, 0, 1.0f);
  k_gemm<<<dim3(8,79), 256, 0, stream>>>(q2, fW1, fb1, nullptr, hbuf, nullptr, NQ, 512, 256, 1, 0, 1.0f);
  k_gemm<<<dim3(4,79), 256, 0, stream>>>(hbuf, fW2, fb2, nullptr, h2, nullptr, NQ, 256, 512, 0, 0, 1.0f);
  k_ln<<<NQ, 256, 0, stream>>>(h2, n2g, n2b, q2, out);
}

// Round 7
// 149.688 us; speedup vs baseline: 5.0613x; 1.1341x over previous
//
#include <hip/hip_runtime.h>
#include <hip/hip_bf16.h>
#include <math.h>

#define NQ   2500
#define CDIM 256
#define NKV  5000
#define NH   8
#define DH   32
#define SPLITS 10
#define KPS   500          // keys per split
#define FULLT 7            // 7 full 64-key tiles
#define TAILNK 52          // 500 - 7*64

typedef __attribute__((ext_vector_type(8))) short bf16x8;
typedef __attribute__((ext_vector_type(4))) short short4v;
typedef __attribute__((ext_vector_type(4))) float f32x4;

#define MFMA __builtin_amdgcn_mfma_f32_16x16x32_bf16

__device__ __forceinline__ short f2bf(float f) {          // RNE
  union { float f; unsigned u; } v; v.f = f;
  unsigned r = v.u + 0x7FFFu + ((v.u >> 16) & 1u);
  return (short)(r >> 16);
}
__device__ __forceinline__ float bf2f(unsigned short s) {
  union { unsigned u; float f; } x; x.u = ((unsigned)s) << 16; return x.f;
}
__device__ __forceinline__ unsigned pk_trunc(float a, float b) { // [lo=a, hi=b], truncation
  union { float f; unsigned u; } x, y; x.f = a; y.f = b;
  return (y.u & 0xFFFF0000u) | (x.u >> 16);
}
__device__ __forceinline__ unsigned cvt_pk_bf16(float a, float b) { // RNE packed (order-safe use only)
  unsigned r;
  asm("v_cvt_pk_bf16_f32 %0, %1, %2" : "=v"(r) : "v"(a), "v"(b));
  return r;
}
__device__ __forceinline__ float exp2_fast(float x) {
  float r; asm("v_exp_f32 %0, %1" : "=v"(r) : "v"(x)); return r;
}
__device__ __forceinline__ bf16x8 cat4(short4v a, short4v b) {
  bf16x8 r;
  r[0]=a[0]; r[1]=a[1]; r[2]=a[2]; r[3]=a[3];
  r[4]=b[0]; r[5]=b[1]; r[6]=b[2]; r[7]=b[3];
  return r;
}

// ---------------- build kv = [query ; warp_prev(prev_bev)] (f32) ----------------
__global__ __launch_bounds__(256) void k_build_kv(
    const float* __restrict__ query, const float* __restrict__ prev,
    const float* __restrict__ ego, float* __restrict__ kv)
{
  int row = blockIdx.x, c = threadIdx.x;
  if (row < NQ) { kv[(size_t)row*CDIM + c] = query[(size_t)row*CDIM + c]; return; }
  int n = row - NQ;
  float txm = ego[3], tym = ego[7];
  float yaw = atan2f(ego[4], ego[0]);
  float cs = cosf(yaw), sn = sinf(yaw);
  float dx = txm * (1.f/51.2f), dy = tym * (1.f/51.2f);
  int i = n / 50, j = n % 50;
  float gx = (2.f*j + 1.f)*(1.f/50.f) - 1.f;
  float gy = (2.f*i + 1.f)*(1.f/50.f) - 1.f;
  float px = cs*gx - sn*gy + dx;
  float py = sn*gx + cs*gy + dy;
  float xf = ((px + 1.f)*50.f - 1.f)*0.5f;
  float yf = ((py + 1.f)*50.f - 1.f)*0.5f;
  float x0f = floorf(xf), y0f = floorf(yf);
  int x0 = (int)x0f, y0 = (int)y0f;
  float wx = xf - x0f, wy = yf - y0f;
  float v00 = (x0  >=0 && x0  <50 && y0  >=0 && y0  <50) ? prev[((size_t)(y0*50+x0      ))*CDIM + c] : 0.f;
  float v10 = (x0+1>=0 && x0+1<50 && y0  >=0 && y0  <50) ? prev[((size_t)(y0*50+x0+1    ))*CDIM + c] : 0.f;
  float v01 = (x0  >=0 && x0  <50 && y0+1>=0 && y0+1<50) ? prev[((size_t)((y0+1)*50+x0  ))*CDIM + c] : 0.f;
  float v11 = (x0+1>=0 && x0+1<50 && y0+1>=0 && y0+1<50) ? prev[((size_t)((y0+1)*50+x0+1))*CDIM + c] : 0.f;
  float v = (v00*(1.f-wx) + v10*wx)*(1.f-wy) + (v01*(1.f-wx) + v11*wx)*wy;
  kv[(size_t)row*CDIM + c] = v;
}

// ---------------- img_feats (6,256,28,50) -> imgT (6,28,50,256) bf16 ----------------
__global__ __launch_bounds__(256) void k_transpose_img(
    const float* __restrict__ img, unsigned short* __restrict__ imgT)
{
  int b = blockIdx.x;          // n*28 + y
  int n = b / 28, y = b % 28;
  int c = threadIdx.x;
  for (int x = 0; x < 50; ++x)
    imgT[((size_t)((n*28 + y)*50 + x))*CDIM + c] =
      (unsigned short)f2bf(img[((size_t)(n*CDIM + c)*28 + y)*50 + x]);
}

// ---------------- MFMA GEMM: C = act(A(MxK) @ W(NxK)^T + bias [+res]) ----------------
// mode 0: C f32 row-major (+res, +relu). mode 1: Cb bf16 row-major ×scale. mode 2: Cb bf16 [N][M].
// BM=32, BN=64, BK=64, 4 waves (each 16x32). Padded LDS rows -> <=2-way staging conflicts.
__global__ __launch_bounds__(256) void k_gemm(
    const float* __restrict__ A, const float* __restrict__ W,
    const float* __restrict__ bias, const float* __restrict__ res,
    float* __restrict__ C, short* __restrict__ Cb,
    int M, int N, int K, int relu, int mode, float scale)
{
  __shared__ short Abf[8][33][8];   // [kgroup][row][8], row-padded
  __shared__ short Wbf[8][65][8];
  const int tid = threadIdx.x;
  const int lane = tid & 63, wid = tid >> 6;
  const int wm = wid >> 1, wn = wid & 1;
  const int g = lane >> 4, c = lane & 15;
  const int m0 = blockIdx.y << 5, n0 = blockIdx.x << 6;
  const int srow = tid >> 3, skq = tid & 7;
  f32x4 acc0 = {0.f,0.f,0.f,0.f}, acc1 = acc0;
  const float4 z4 = make_float4(0.f,0.f,0.f,0.f);
  for (int k0 = 0; k0 < K; k0 += 64) {
    float4 fa0 = z4, fa1 = z4;
    if (m0 + srow < M) {
      const float* ap = A + (size_t)(m0+srow)*K + k0 + skq*8;
      fa0 = *(const float4*)ap; fa1 = *(const float4*)(ap+4);
    }
    const float* wp0 = W + (size_t)(n0+srow)*K + k0 + skq*8;
    const float* wp1 = W + (size_t)(n0+32+srow)*K + k0 + skq*8;
    const float4 fw00 = *(const float4*)wp0, fw01 = *(const float4*)(wp0+4);
    const float4 fw10 = *(const float4*)wp1, fw11 = *(const float4*)(wp1+4);
    __syncthreads();   // prev iteration's frag reads done
    union { unsigned u[4]; bf16x8 v; } pa, pw0, pw1;
    pa.u[0]  = cvt_pk_bf16(fa0.x, fa0.y);  pa.u[1]  = cvt_pk_bf16(fa0.z, fa0.w);
    pa.u[2]  = cvt_pk_bf16(fa1.x, fa1.y);  pa.u[3]  = cvt_pk_bf16(fa1.z, fa1.w);
    pw0.u[0] = cvt_pk_bf16(fw00.x, fw00.y); pw0.u[1] = cvt_pk_bf16(fw00.z, fw00.w);
    pw0.u[2] = cvt_pk_bf16(fw01.x, fw01.y); pw0.u[3] = cvt_pk_bf16(fw01.z, fw01.w);
    pw1.u[0] = cvt_pk_bf16(fw10.x, fw10.y); pw1.u[1] = cvt_pk_bf16(fw10.z, fw10.w);
    pw1.u[2] = cvt_pk_bf16(fw11.x, fw11.y); pw1.u[3] = cvt_pk_bf16(fw11.z, fw11.w);
    *(bf16x8*)&Abf[skq][srow][0]      = pa.v;
    *(bf16x8*)&Wbf[skq][srow][0]      = pw0.v;
    *(bf16x8*)&Wbf[skq][32+srow][0]   = pw1.v;
    __syncthreads();
    #pragma unroll
    for (int s = 0; s < 2; ++s) {
      const bf16x8 fA  = *(const bf16x8*)&Abf[s*4+g][wm*16 + c][0];
      const bf16x8 fW0 = *(const bf16x8*)&Wbf[s*4+g][wn*32 + c][0];
      const bf16x8 fW1 = *(const bf16x8*)&Wbf[s*4+g][wn*32 + 16 + c][0];
      acc0 = MFMA(fA, fW0, acc0, 0,0,0);
      acc1 = MFMA(fA, fW1, acc1, 0,0,0);
    }
  }
  const int nc0 = n0 + wn*32 + c, nc1 = nc0 + 16;
  const float b0v = bias[nc0], b1v = bias[nc1];
  #pragma unroll
  for (int r = 0; r < 4; ++r) {
    const int m = m0 + wm*16 + g*4 + r;
    if (m >= M) continue;
    float v0 = acc0[r] + b0v;
    float v1 = acc1[r] + b1v;
    if (mode == 0) {
      if (res) { v0 += res[(size_t)m*N + nc0]; v1 += res[(size_t)m*N + nc1]; }
      if (relu) { v0 = fmaxf(v0, 0.f); v1 = fmaxf(v1, 0.f); }
      C[(size_t)m*N + nc0] = v0;
      C[(size_t)m*N + nc1] = v1;
    } else if (mode == 1) {
      Cb[(size_t)m*N + nc0] = f2bf(v0*scale);
      Cb[(size_t)m*N + nc1] = f2bf(v1*scale);
    } else {
      Cb[(size_t)nc0*M + m] = f2bf(v0);
      Cb[(size_t)nc1*M + m] = f2bf(v1);
    }
  }
}

// ---------------- flash softmax+PV step, T13 defer-max, lane-local l ----------------
__device__ __forceinline__ void softmax_pv(
    f32x4 s0, f32x4 s1, f32x4 s2, f32x4 s3, bool tail, int g,
    float& m, float& l, f32x4& oA, f32x4& oB,
    bf16x8 A0lo, bf16x8 A0hi, bf16x8 A1lo, bf16x8 A1hi)
{
  float sv[16];
  #pragma unroll
  for (int r=0;r<4;++r){ sv[r]=s0[r]; sv[4+r]=s1[r]; sv[8+r]=s2[r]; sv[12+r]=s3[r]; }
  if (tail) {
    #pragma unroll
    for (int i=0;i<16;++i) {
      const int kl = (i>>2)*16 + g*4 + (i&3);
      if (kl >= TAILNK) sv[i] = -1e30f;
    }
  }
  // lane-local max over this lane's 16 scores
  float mx = fmaxf(fmaxf(fmaxf(sv[0],sv[1]),fmaxf(sv[2],sv[3])),
                   fmaxf(fmaxf(sv[4],sv[5]),fmaxf(sv[6],sv[7])));
  mx = fmaxf(mx, fmaxf(fmaxf(fmaxf(sv[8],sv[9]),fmaxf(sv[10],sv[11])),
                       fmaxf(fmaxf(sv[12],sv[13]),fmaxf(sv[14],sv[15]))));
  // T13: only rescale when the running max actually needs to grow (wave-uniform)
  if (!__all(mx <= m + 8.f)) {
    float mm = fmaxf(mx, __shfl_xor(mx, 16));
    mm = fmaxf(mm, __shfl_xor(mm, 32));
    const float mn = fmaxf(m, mm);
    const float scl = exp2_fast(m - mn);   // first tile: exp2(-inf)=0
    m = mn;
    l *= scl;
    #pragma unroll
    for (int r=0;r<4;++r){ oA[r]*=scl; oB[r]*=scl; }
  }
  float p[16]; float ps = 0.f;
  #pragma unroll
  for (int i=0;i<16;++i){ p[i] = exp2_fast(sv[i]-m); ps += p[i]; }
  l += ps;                     // lane-local partial sum; combined across g at the end
  union { unsigned u[4]; bf16x8 v; } b0, b1;
  #pragma unroll
  for (int i=0;i<4;++i) {
    b0.u[i] = pk_trunc(p[2*i],   p[2*i+1]);
    b1.u[i] = pk_trunc(p[8+2*i], p[8+2*i+1]);
  }
  oA = MFMA(A0lo, b0.v, oA, 0,0,0);
  oA = MFMA(A0hi, b1.v, oA, 0,0,0);
  oB = MFMA(A1lo, b0.v, oB, 0,0,0);
  oB = MFMA(A1hi, b1.v, oB, 0,0,0);
}

// ---------------- bf16 MFMA flash attention: 1-WAVE blocks, 32 q/wave ----------------
// grid (79, NH, SPLITS) x 64 threads. VbfT path (round-4-proven). K-prefetch pipeline.
__global__ __launch_bounds__(64) void k_flash4(
    const short* __restrict__ Qbf, const short* __restrict__ Kbf,
    const short* __restrict__ VbfT, short* __restrict__ opart,
    float* __restrict__ mlp)
{
  const int lane = threadIdx.x;
  const int g = lane >> 4, c = lane & 15;
  const int h = blockIdx.y, sp = blockIdx.z;
  const int q0 = blockIdx.x * 32;
  const int qa  = min(q0 +      c, NQ-1);
  const int qb2 = min(q0 + 16 + c, NQ-1);
  const bf16x8 qf0 = *(const bf16x8*)(Qbf + (size_t)qa *CDIM + h*DH + g*8);
  const bf16x8 qf1 = *(const bf16x8*)(Qbf + (size_t)qb2*CDIM + h*DH + g*8);
  const int kbase = sp*KPS;
  const size_t doff = (size_t)h*DH + g*8;
  const short* kbp = Kbf + (size_t)(kbase + c)*CDIM + doff;
  const short* vr0 = VbfT + (size_t)(h*DH +      c)*NKV + kbase;
  const short* vr1 = VbfT + (size_t)(h*DH + 16 + c)*NKV + kbase;
  const f32x4 z = {0.f,0.f,0.f,0.f};
  f32x4 o00 = z, o01 = z, o10 = z, o11 = z;
  float m0v = -INFINITY, l0 = 0.f, m1v = -INFINITY, l1 = 0.f;

  // prologue: K tile 0
  bf16x8 kc0 = *(const bf16x8*)(kbp);
  bf16x8 kc1 = *(const bf16x8*)(kbp + (size_t)16*CDIM);
  bf16x8 kc2 = *(const bf16x8*)(kbp + (size_t)32*CDIM);
  bf16x8 kc3 = *(const bf16x8*)(kbp + (size_t)48*CDIM);

  #pragma unroll
  for (int t = 0; t < FULLT; ++t) {
    const int kt = t*64;
    const f32x4 s00 = MFMA(kc0, qf0, z, 0,0,0);
    const f32x4 s01 = MFMA(kc1, qf0, z, 0,0,0);
    const f32x4 s02 = MFMA(kc2, qf0, z, 0,0,0);
    const f32x4 s03 = MFMA(kc3, qf0, z, 0,0,0);
    const f32x4 s10 = MFMA(kc0, qf1, z, 0,0,0);
    const f32x4 s11 = MFMA(kc1, qf1, z, 0,0,0);
    const f32x4 s12 = MFMA(kc2, qf1, z, 0,0,0);
    const f32x4 s13 = MFMA(kc3, qf1, z, 0,0,0);
    if (t+1 < FULLT) {   // prefetch next full K tile (in flight during softmax/PV)
      kc0 = *(const bf16x8*)(kbp + (size_t)(kt+64)*CDIM);
      kc1 = *(const bf16x8*)(kbp + (size_t)(kt+80)*CDIM);
      kc2 = *(const bf16x8*)(kbp + (size_t)(kt+96)*CDIM);
      kc3 = *(const bf16x8*)(kbp + (size_t)(kt+112)*CDIM);
    }
    const short4v x00 = *(const short4v*)(vr0 + kt      + g*4);
    const short4v x01 = *(const short4v*)(vr0 + kt + 16 + g*4);
    const short4v x02 = *(const short4v*)(vr0 + kt + 32 + g*4);
    const short4v x03 = *(const short4v*)(vr0 + kt + 48 + g*4);
    const short4v x10 = *(const short4v*)(vr1 + kt      + g*4);
    const short4v x11 = *(const short4v*)(vr1 + kt + 16 + g*4);
    const short4v x12 = *(const short4v*)(vr1 + kt + 32 + g*4);
    const short4v x13 = *(const short4v*)(vr1 + kt + 48 + g*4);
    const bf16x8 A0lo = cat4(x00, x01), A0hi = cat4(x02, x03);
    const bf16x8 A1lo = cat4(x10, x11), A1hi = cat4(x12, x13);
    softmax_pv(s00,s01,s02,s03, false, g, m0v, l0, o00, o01, A0lo, A0hi, A1lo, A1hi);
    softmax_pv(s10,s11,s12,s13, false, g, m1v, l1, o10, o11, A0lo, A0hi, A1lo, A1hi);
  }
  { // tail tile: 52 valid keys, clamped addresses, masked softmax
    const int kt = FULLT*64;   // 448
    const int ka0 = min(kbase + kt +      c, NKV-1);
    const int ka1 = min(kbase + kt + 16 + c, NKV-1);
    const int ka2 = min(kbase + kt + 32 + c, NKV-1);
    const int ka3 = min(kbase + kt + 48 + c, NKV-1);
    const bf16x8 kf0 = *(const bf16x8*)(Kbf + (size_t)ka0*CDIM + doff);
    const bf16x8 kf1 = *(const bf16x8*)(Kbf + (size_t)ka1*CDIM + doff);
    const bf16x8 kf2 = *(const bf16x8*)(Kbf + (size_t)ka2*CDIM + doff);
    const bf16x8 kf3 = *(const bf16x8*)(Kbf + (size_t)ka3*CDIM + doff);
    const f32x4 s00 = MFMA(kf0, qf0, z, 0,0,0);
    const f32x4 s01 = MFMA(kf1, qf0, z, 0,0,0);
    const f32x4 s02 = MFMA(kf2, qf0, z, 0,0,0);
    const f32x4 s03 = MFMA(kf3, qf0, z, 0,0,0);
    const f32x4 s10 = MFMA(kf0, qf1, z, 0,0,0);
    const f32x4 s11 = MFMA(kf1, qf1, z, 0,0,0);
    const f32x4 s12 = MFMA(kf2, qf1, z, 0,0,0);
    const f32x4 s13 = MFMA(kf3, qf1, z, 0,0,0);
    const int o0 = min(kt      + g*4, KPS-4);
    const int o1 = min(kt + 16 + g*4, KPS-4);
    const int o2 = min(kt + 32 + g*4, KPS-4);
    const int o3 = min(kt + 48 + g*4, KPS-4);
    const short4v x00 = *(const short4v*)(vr0 + o0);
    const short4v x01 = *(const short4v*)(vr0 + o1);
    const short4v x02 = *(const short4v*)(vr0 + o2);
    const short4v x03 = *(const short4v*)(vr0 + o3);
    const short4v x10 = *(const short4v*)(vr1 + o0);
    const short4v x11 = *(const short4v*)(vr1 + o1);
    const short4v x12 = *(const short4v*)(vr1 + o2);
    const short4v x13 = *(const short4v*)(vr1 + o3);
    const bf16x8 A0lo = cat4(x00, x01), A0hi = cat4(x02, x03);
    const bf16x8 A1lo = cat4(x10, x11), A1hi = cat4(x12, x13);
    softmax_pv(s00,s01,s02,s03, true, g, m0v, l0, o00, o01, A0lo, A0hi, A1lo, A1hi);
    softmax_pv(s10,s11,s12,s13, true, g, m1v, l1, o10, o11, A0lo, A0hi, A1lo, A1hi);
  }
  // combine lane-local l across the 4 g-lanes of each q-column
  l0 += __shfl_xor(l0, 16); l0 += __shfl_xor(l0, 32);
  l1 += __shfl_xor(l1, 16); l1 += __shfl_xor(l1, 32);

  const size_t ob0 = (size_t)(sp*NH + h)*NQ;
  const int qw0 = q0 + c;
  if (qw0 < NQ) {
    const size_t b = (ob0 + qw0)*DH;
    #pragma unroll
    for (int r=0;r<4;++r) {
      opart[b +      g*4 + r] = f2bf(o00[r]);
      opart[b + 16 + g*4 + r] = f2bf(o01[r]);
    }
    if (g == 0) { mlp[(ob0 + qw0)*2] = m0v; mlp[(ob0 + qw0)*2+1] = l0; }
  }
  const int qw1 = q0 + 16 + c;
  if (qw1 < NQ) {
    const size_t b = (ob0 + qw1)*DH;
    #pragma unroll
    for (int r=0;r<4;++r) {
      opart[b +      g*4 + r] = f2bf(o10[r]);
      opart[b + 16 + g*4 + r] = f2bf(o11[r]);
    }
    if (g == 0) { mlp[(ob0 + qw1)*2] = m1v; mlp[(ob0 + qw1)*2+1] = l1; }
  }
}

// ---------------- combine split partials (exp2 domain) ----------------
__global__ __launch_bounds__(256) void k_combine(
    const short* __restrict__ opart, const float* __restrict__ mlp,
    float* __restrict__ attn)
{
  const int q = blockIdx.x, t = threadIdx.x;
  const int h = t >> 5, d = t & 31;
  float ms[SPLITS], ls[SPLITS];
  float mstar = -INFINITY;
  #pragma unroll
  for (int s = 0; s < SPLITS; ++s) {
    size_t b = (size_t)(s*NH + h)*NQ + q;
    ms[s] = mlp[b*2]; ls[s] = mlp[b*2+1];
    mstar = fmaxf(mstar, ms[s]);
  }
  float num = 0.f, den = 0.f;
  #pragma unroll
  for (int s = 0; s < SPLITS; ++s) {
    float e = exp2_fast(ms[s] - mstar);
    size_t b = (size_t)(s*NH + h)*NQ + q;
    num += bf2f((unsigned short)opart[b*DH + d])*e;
    den += ls[s]*e;
  }
  attn[(size_t)q*CDIM + t] = num/den;
}

// ---------------- row LayerNorm: out = [post_res +] LN(x)*g + b ----------------
__global__ __launch_bounds__(256) void k_ln(
    const float* __restrict__ x, const float* __restrict__ g,
    const float* __restrict__ b, const float* __restrict__ post_res,
    float* __restrict__ out)
{
  const int row = blockIdx.x, c = threadIdx.x;
  const size_t idx = (size_t)row*CDIM + c;
  const float v = x[idx];
  __shared__ float red[4];
  float s = v;
  #pragma unroll
  for (int m = 1; m < 64; m <<= 1) s += __shfl_xor(s, m);
  if ((c & 63) == 0) red[c >> 6] = s;
  __syncthreads();
  const float mean = (red[0]+red[1]+red[2]+red[3]) * (1.f/256.f);
  const float dv = v - mean;
  __syncthreads();
  float s2 = dv*dv;
  #pragma unroll
  for (int m = 1; m < 64; m <<= 1) s2 += __shfl_xor(s2, m);
  if ((c & 63) == 0) red[c >> 6] = s2;
  __syncthreads();
  const float var = (red[0]+red[1]+red[2]+red[3]) * (1.f/256.f);
  float o = dv * rsqrtf(var + 1e-5f) * g[c] + b[c];
  if (post_res) o += post_res[idx];
  out[idx] = o;
}

// ---------------- fused attn_w GEMV + softmax(24) + point sampling + agg ----------------
__global__ __launch_bounds__(256) void k_sample_agg(
    const float* __restrict__ q1, const unsigned short* __restrict__ imgT,
    const float* __restrict__ l2i, const float* __restrict__ awW,
    const float* __restrict__ awb, float* __restrict__ agg)
{
  const int q = blockIdx.x, tid = threadIdx.x;
  __shared__ float qrow[256];
  __shared__ float wl[24];
  __shared__ float fwx[24], fwy[24];
  __shared__ int iv[24], ix[24], iy[24];
  qrow[tid] = q1[(size_t)q*CDIM + tid];
  __syncthreads();
  if (tid < 192) {
    const int e = tid >> 3, s2 = tid & 7;
    float acc = 0.f;
    for (int c = s2; c < 256; c += 8) acc += qrow[c]*awW[e*256 + c];
    acc += __shfl_xor(acc,1);
    acc += __shfl_xor(acc,2);
    acc += __shfl_xor(acc,4);
    if (s2 == 0) wl[e] = acc + awb[e];
  }
  if (tid < 24) {
    const int e = tid, n = e >> 2, z = e & 3;
    const int iyq = q / 50, jxq = q % 50;
    const float rx = (jxq + 0.5f)*(1.f/50.f);
    const float ry = (iyq + 0.5f)*(1.f/50.f);
    const float rz = (z + 0.5f)*0.25f;
    const float X = rx*102.4f - 51.2f;
    const float Y = ry*102.4f - 51.2f;
    const float Z = rz*8.f - 5.f;
    const float* L = l2i + n*16;
    const float cx = L[0]*X + L[1]*Y + L[2]*Z  + L[3];
    const float cy = L[4]*X + L[5]*Y + L[6]*Z  + L[7];
    const float cd = L[8]*X + L[9]*Y + L[10]*Z + L[11];
    const float dn = fmaxf(cd, 1e-5f);
    const float u = cx/dn, vv = cy/dn;
    const float gx = (u*(1.f/49.f) - 0.5f)*2.f;
    const float gy = (vv*(1.f/27.f) - 0.5f)*2.f;
    const int ok = (cd > 1e-5f) && (gx > -1.f) && (gx < 1.f) && (gy > -1.f) && (gy < 1.f);
    const float xf = ((gx + 1.f)*50.f - 1.f)*0.5f;
    const float yf = ((gy + 1.f)*28.f - 1.f)*0.5f;
    const float x0f = floorf(xf), y0f = floorf(yf);
    iv[e] = ok; ix[e] = (int)x0f; iy[e] = (int)y0f;
    fwx[e] = xf - x0f; fwy[e] = yf - y0f;
  }
  __syncthreads();
  float mx = -INFINITY;
  #pragma unroll
  for (int e = 0; e < 24; ++e) mx = fmaxf(mx, wl[e]);
  float se = 0.f;
  #pragma unroll
  for (int e = 0; e < 24; ++e) se += __expf(wl[e]-mx);
  const float inv = 1.f/se;
  const int c = tid;
  float acc = 0.f;
  #pragma unroll
  for (int e = 0; e < 24; ++e) {
    if (!iv[e]) continue;
    const float w = __expf(wl[e]-mx)*inv;
    const int n = e >> 2;
    const int x0 = ix[e], y0 = iy[e];
    const float wx = fwx[e], wy = fwy[e];
    const size_t base = (size_t)(n*28)*50;
    float v00 = (x0  >=0 && x0  <50 && y0  >=0 && y0  <28) ? bf2f(imgT[((base + (size_t)y0*50     + x0  ))*CDIM + c]) : 0.f;
    float v10 = (x0+1>=0 && x0+1<50 && y0  >=0 && y0  <28) ? bf2f(imgT[((base + (size_t)y0*50     + x0+1))*CDIM + c]) : 0.f;
    float v01 = (x0  >=0 && x0  <50 && y0+1>=0 && y0+1<28) ? bf2f(imgT[((base + (size_t)(y0+1)*50 + x0  ))*CDIM + c]) : 0.f;
    float v11 = (x0+1>=0 && x0+1<50 && y0+1>=0 && y0+1<28) ? bf2f(imgT[((base + (size_t)(y0+1)*50 + x0+1))*CDIM + c]) : 0.f;
    acc += w * ((v00*(1.f-wx) + v10*wx)*(1.f-wy) + (v01*(1.f-wx) + v11*wx)*wy);
  }
  agg[(size_t)q*CDIM + c] = acc;
}

// ---------------- launcher ----------------
extern "C" void kernel_launch(void* const* d_in, const int* in_sizes, int n_in,
                              void* d_out, int out_size, void* d_ws, size_t ws_size,
                              hipStream_t stream)
{
  const float* query = (const float*)d_in[0];
  const float* prev  = (const float*)d_in[1];
  const float* img   = (const float*)d_in[2];
  const float* ego   = (const float*)d_in[3];
  const float* l2i   = (const float*)d_in[4];
  const float* awW   = (const float*)d_in[5];
  const float* awb   = (const float*)d_in[6];
  const float* scaW  = (const float*)d_in[7];
  const float* scab  = (const float*)d_in[8];
  const float* inW   = (const float*)d_in[9];
  const float* inb   = (const float*)d_in[10];
  const float* moW   = (const float*)d_in[11];
  const float* mob   = (const float*)d_in[12];
  const float* n1g   = (const float*)d_in[13];
  const float* n1b   = (const float*)d_in[14];
  const float* fW1   = (const float*)d_in[15];
  const float* fb1   = (const float*)d_in[16];
  const float* fW2   = (const float*)d_in[17];
  const float* fb2   = (const float*)d_in[18];
  const float* n2g   = (const float*)d_in[19];
  const float* n2b   = (const float*)d_in[20];
  float* out = (float*)d_out;
  float* ws  = (float*)d_ws;

  // ---- workspace layout (float offsets); total 7,555,200 f = 30.2 MB ----
  // phase A:
  float* kv    = ws;                        // [5000,256] f32   [0,        1280000)
  short* Qbf   = (short*)(ws + 1280000);    // [2500,256] bf16  [1280000,  1600000)
  short* Kbf   = (short*)(ws + 1600000);    // [5000,256] bf16  [1600000,  2240000)
  short* VbfT  = (short*)(ws + 2240000);    // [256,5000] bf16  [2240000,  2880000)
  short* opart = (short*)(ws + 2880000);    // [10,8,2500,32]   [2880000,  6080000)
  float* mlp   = ws + 6080000;              // [10,8,2500,2]    [6080000,  6480000)
  unsigned short* imgT = (unsigned short*)(ws + 6480000); // [6,28,50,256] [6480000, 7555200)
  // phase B (reuse of dead regions; every dispatch's reads/writes disjoint):
  float* attn  = ws;                        // [2500,256] f32   [0,       640000)  (kv dead)
  float* tmp1  = ws +  640000;              // [2500,256] f32   [640000, 1280000)  (kv dead)
  float* q1    = ws + 1280000;              // [2500,256] f32   [1280000,1920000)  (Qbf/Kbf dead)
  float* aggb  = ws + 1920000;              // [2500,256] f32   [1920000,2560000)  (Kbf/VbfT dead)
  float* q2    = ws + 2560000;              // [2500,256] f32   [2560000,3200000)  (VbfT/opart dead)
  float* hbuf  = ws + 3200000;              // [2500,512] f32   [3200000,4480000)  (opart dead)
  float* h2    = ws + 4480000;              // [2500,256] f32   [4480000,5120000)  (opart dead)

  const float qscale = 0.2550727452794943f;  // (1/sqrt(32)) * log2(e)

  k_build_kv<<<NKV, 256, 0, stream>>>(query, prev, ego, kv);
  k_transpose_img<<<6*28, 256, 0, stream>>>(img, imgT);
  k_gemm<<<dim3(4,79),  256, 0, stream>>>(kv, inW,          inb,     nullptr, nullptr, Qbf,  NQ,  256, 256, 0, 1, qscale);
  k_gemm<<<dim3(4,157), 256, 0, stream>>>(kv, inW + 65536,  inb+256, nullptr, nullptr, Kbf,  NKV, 256, 256, 0, 1, 1.0f);
  k_gemm<<<dim3(4,157), 256, 0, stream>>>(kv, inW + 131072, inb+512, nullptr, nullptr, VbfT, NKV, 256, 256, 0, 2, 1.0f);
  k_flash4<<<dim3(79, NH, SPLITS), 64, 0, stream>>>(Qbf, Kbf, VbfT, opart, mlp);
  k_combine<<<NQ, 256, 0, stream>>>(opart, mlp, attn);
  k_gemm<<<dim3(4,79), 256, 0, stream>>>(attn, moW, mob, query, tmp1, nullptr, NQ, 256, 256, 0, 0, 1.0f);
  k_ln<<<NQ, 256, 0, stream>>>(tmp1, n1g, n1b, nullptr, q1);
  k_sample_agg<<<NQ, 256, 0, stream>>>(q1, imgT, l2i, awW, awb, aggb);
  k_gemm<<<dim3(4,79), 256, 0, stream>>>(aggb, scaW, scab, q1, q2, nullptr, NQ, 256, 256, 0, 0, 1.0f);
  k_gemm<<<dim3(8,79), 256, 0, stream>>>(q2, fW1, fb1, nullptr, hbuf, nullptr, NQ, 512, 256, 1, 0, 1.0f);
  k_gemm<<<dim3(4,79), 256, 0, stream>>>(hbuf, fW2, fb2, nullptr, h2, nullptr, NQ, 256, 512, 0, 0, 1.0f);
  k_ln<<<NQ, 256, 0, stream>>>(h2, n2g, n2b, q2, out);
}